// Round 3
// baseline (474.602 us; speedup 1.0000x reference)
//
#include <hip/hip_runtime.h>
#include <hip/hip_bf16.h>
#include <cstdint>
#include <cstddef>

#define T_ 512
#define DF 64
#define NPAIR 120
#define STEPW 16
#define BIG_ 1e10f

// softmin constants: exp((m-x)/g) = exp2((m-x)*log2(e)/g); g*ln(2)
#define C1_ 0.28853900817779268f   // log2(e)/5
#define C2_ 3.4657359027997265f    // 5*ln(2)

__device__ __forceinline__ float wred_sum(float v) {
#pragma unroll
  for (int o = 32; o > 0; o >>= 1) v += __shfl_down(v, o);
  return v;  // lane 0 holds the total
}

// ---------------------------------------------------------------------------
// Kernel 1: pairwise sq-dist GEMM, plain row-major output D[pc][i][j].
// Block: one 64x64 tile of one pair, 256 threads, K = DF = 64.
// ---------------------------------------------------------------------------
__global__ __launch_bounds__(256) void gemm_kernel(
    const float* __restrict__ data, float* __restrict__ dsk, int pair0) {
  __shared__ float Xs[64][65];
  __shared__ float Ys[64][65];
  __shared__ float nrmx[64];
  __shared__ float nrmy[64];

  const int tile = blockIdx.x;   // 0..63 = (bi<<3)|bj
  const int pc = blockIdx.y;     // pair within chunk
  const int p = pair0 + pc;
  const int w = p / 15;
  const int o = p - w * 15;
  const int aidx = w * STEPW;
  const int oidx = aidx + 1 + o;
  const int i0 = (tile >> 3) << 6;
  const int j0 = (tile & 7) << 6;
  const int tid = threadIdx.x;

  const float* Xg = data + (size_t)aidx * (T_ * DF);
  const float* Yg = data + (size_t)oidx * (T_ * DF);

#pragma unroll
  for (int l = 0; l < 4; ++l) {
    int idx = tid + l * 256;  // 0..1023
    int r = idx >> 4;
    int c = idx & 15;
    float4 xv = reinterpret_cast<const float4*>(Xg + (size_t)(i0 + r) * DF)[c];
    float4 yv = reinterpret_cast<const float4*>(Yg + (size_t)(j0 + r) * DF)[c];
    Xs[r][4 * c + 0] = xv.x; Xs[r][4 * c + 1] = xv.y;
    Xs[r][4 * c + 2] = xv.z; Xs[r][4 * c + 3] = xv.w;
    Ys[r][4 * c + 0] = yv.x; Ys[r][4 * c + 1] = yv.y;
    Ys[r][4 * c + 2] = yv.z; Ys[r][4 * c + 3] = yv.w;
  }
  __syncthreads();

  if (tid < 128) {
    int r = tid & 63;
    const float* row = (tid < 64) ? Xs[r] : Ys[r];
    float s = 0.f;
#pragma unroll
    for (int k = 0; k < 64; ++k) s = fmaf(row[k], row[k], s);
    if (tid < 64) nrmx[r] = s; else nrmy[r] = s;
  }
  __syncthreads();

  const int tx = tid & 15;
  const int ty = tid >> 4;
  float acc[4][4];
#pragma unroll
  for (int a = 0; a < 4; ++a)
#pragma unroll
    for (int b = 0; b < 4; ++b) acc[a][b] = 0.f;

#pragma unroll 4
  for (int k = 0; k < 64; ++k) {
    float xr[4], yr[4];
#pragma unroll
    for (int a = 0; a < 4; ++a) xr[a] = Xs[ty * 4 + a][k];
#pragma unroll
    for (int b = 0; b < 4; ++b) yr[b] = Ys[tx * 4 + b][k];
#pragma unroll
    for (int a = 0; a < 4; ++a)
#pragma unroll
      for (int b = 0; b < 4; ++b) acc[a][b] = fmaf(xr[a], yr[b], acc[a][b]);
  }

  // epilogue: coalesced row-major float4 stores (16 lanes x 16B = 256B rows)
  float* Dp = dsk + (size_t)pc * (T_ * T_) + (size_t)i0 * T_ + j0;
#pragma unroll
  for (int a = 0; a < 4; ++a) {
    int ii = ty * 4 + a;
    float nx = nrmx[ii];
    float4 v;
    v.x = nx + nrmy[tx * 4 + 0] - 2.f * acc[a][0];
    v.y = nx + nrmy[tx * 4 + 1] - 2.f * acc[a][1];
    v.z = nx + nrmy[tx * 4 + 2] - 2.f * acc[a][2];
    v.w = nx + nrmy[tx * 4 + 3] - 2.f * acc[a][3];
    *reinterpret_cast<float4*>(Dp + (size_t)ii * T_ + tx * 4) = v;
  }
}

// ---------------------------------------------------------------------------
// Kernel 2: softDTW, ONE WAVE PER PAIR, zero barriers.
// Lane l owns columns [8l, 8l+8). Super-step n: lane l computes row i = n - l
// (8 cells serially; left-dep lane-local). Cross-lane boundary values come
// from lane l-1's last-column register via __shfl_up (wave lockstep):
//   bl  = R[i][8l-1]   (lane l-1 computed it at super-step n-1)
//   blp = R[i-1][8l-1] (lane l-1 computed it at super-step n-2)
// ---------------------------------------------------------------------------
#define CELL(DV, RU)                                      \
  {                                                       \
    float up = RU;                                        \
    float m = fminf(fminf(up, dprev), left);              \
    float e = __builtin_exp2f((m - left) * C1_) +         \
              __builtin_exp2f((m - up) * C1_) +           \
              __builtin_exp2f((m - dprev) * C1_);         \
    float r = fmaf(-C2_, __builtin_log2f(e), (DV) + m);   \
    dprev = up;                                           \
    RU = r;                                               \
    left = r;                                             \
  }

__global__ __launch_bounds__(64) void dtw_kernel(
    const float* __restrict__ dsk, const int* __restrict__ lens,
    float* __restrict__ dist, int pair0) {
  const int pc = blockIdx.x;
  const int p = pair0 + pc;
  const int w = p / 15;
  const int o = p - w * 15;
  const int lx = lens[w * STEPW];
  const int ly = lens[w * STEPW + 1 + o];
  const int l = threadIdx.x;     // lane 0..63
  const int jt = ly - 1;
  const int lt = jt >> 3;        // lane owning target column
  const int ct = jt & 7;
  const int nmax = (lx - 1) + lt;
  const float invl = 1.f / (float)(lx + ly);

  const float* dp = dsk + (size_t)pc * (T_ * T_) + (l << 3);

  // R of previous committed row for my 8 columns
  float ru0 = BIG_, ru1 = BIG_, ru2 = BIG_, ru3 = BIG_;
  float ru4 = BIG_, ru5 = BIG_, ru6 = BIG_, ru7 = BIG_;
  float blp = BIG_;  // boundary value from two super-steps ago

  // D rows, software-pipelined 2 deep (named regs only)
  float4 cur0 = {}, cur1 = {}, nxt0 = {}, nxt1 = {}, pf0 = {}, pf1 = {};
  if (l == 0) {
    cur0 = *reinterpret_cast<const float4*>(dp);
    cur1 = *reinterpret_cast<const float4*>(dp + 4);
  }
  {
    int ip = 1 - l;
    if (ip >= 0) {
      nxt0 = *reinterpret_cast<const float4*>(dp + (size_t)ip * T_);
      nxt1 = *reinterpret_cast<const float4*>(dp + (size_t)ip * T_ + 4);
    }
  }

#pragma unroll 2
  for (int n = 0; n <= nmax; ++n) {
    float bl = __shfl_up(ru7, 1);
    const int i = n - l;
    const int ip = i + 2;
    if (ip >= 0 && ip < T_) {
      pf0 = *reinterpret_cast<const float4*>(dp + (size_t)ip * T_);
      pf1 = *reinterpret_cast<const float4*>(dp + (size_t)ip * T_ + 4);
    }
    if (i >= 0 && i < T_) {
      float left = (l == 0) ? BIG_ : bl;
      float dprev = (l == 0) ? ((i == 0) ? 0.f : BIG_) : blp;
      CELL(cur0.x, ru0); CELL(cur0.y, ru1);
      CELL(cur0.z, ru2); CELL(cur0.w, ru3);
      CELL(cur1.x, ru4); CELL(cur1.y, ru5);
      CELL(cur1.z, ru6); CELL(cur1.w, ru7);
    }
    blp = bl;
    cur0 = nxt0; cur1 = nxt1; nxt0 = pf0; nxt1 = pf1;
  }

  if (l == lt) {
    float rt = (ct == 0) ? ru0 : (ct == 1) ? ru1 : (ct == 2) ? ru2
             : (ct == 3) ? ru3 : (ct == 4) ? ru4 : (ct == 5) ? ru5
             : (ct == 6) ? ru6 : ru7;
    dist[p] = rt * invl;
  }
}

// ---------------------------------------------------------------------------
// Kernel 3: MMD pairwise per-feature L2 (upper triangle, mirrored)
// ---------------------------------------------------------------------------
__global__ __launch_bounds__(64) void mmd_l2_kernel(
    const float* __restrict__ data, float* __restrict__ l2buf,
    float* __restrict__ bwpart) {
  int b = blockIdx.x;  // 0..252 upper-tri (incl diag) index
  int u = 0, rem = b;
  while (rem >= 22 - u) { rem -= 22 - u; ++u; }
  int v = u + rem;
  int f = threadIdx.x;
  float s = 0.f;
  if (u != v) {
    int iu = u < 11 ? u : u + 5;
    int iv = v < 11 ? v : v + 5;
    const float* A = data + (size_t)iu * (T_ * DF) + f;
    const float* B = data + (size_t)iv * (T_ * DF) + f;
#pragma unroll 8
    for (int t = 0; t < T_; ++t) {
      float dd = A[(size_t)t * DF] - B[(size_t)t * DF];
      s = fmaf(dd, dd, s);
    }
  }
  l2buf[(size_t)(u * 22 + v) * 64 + f] = s;
  l2buf[(size_t)(v * 22 + u) * 64 + f] = s;
  float tot = wred_sum(s);
  if (f == 0) bwpart[b] = 2.f * tot;  // diag contributes exactly 0
}

// ---------------------------------------------------------------------------
// Kernel 4: MMD kernel sums per (a,c) of the 11x11 grid
// ---------------------------------------------------------------------------
__global__ __launch_bounds__(64) void mmd_k_kernel(
    const float* __restrict__ l2buf, const float* __restrict__ bwpart,
    float* __restrict__ mmdpart) {
  int b = blockIdx.x;  // 0..120
  int a = b / 11, c = b - a * 11;
  int f = threadIdx.x;
  float bs = 0.f;
  for (int k2 = f; k2 < 253; k2 += 64) bs += bwpart[k2];
  bs = wred_sum(bs);
  float bw = __shfl(bs, 0) * (1.f / (462.f * 4.f));  // /(n^2-n)/KMUL^(KNUM//2)
  float xx = l2buf[(size_t)(a * 22 + c) * 64 + f];
  float yy = l2buf[(size_t)((11 + a) * 22 + (11 + c)) * 64 + f];
  float xy = l2buf[(size_t)(a * 22 + (11 + c)) * 64 + f];
  float yx = l2buf[(size_t)((11 + a) * 22 + c) * 64 + f];
  float term = 0.f;
  float ib = 1.f / bw;
#pragma unroll
  for (int i = 0; i < 5; ++i) {
    term += expf(-xx * ib) + expf(-yy * ib) - expf(-xy * ib) - expf(-yx * ib);
    ib *= 0.5f;
  }
  float tt = wred_sum(term);
  if (f == 0) mmdpart[b] = tt;
}

// ---------------------------------------------------------------------------
// Kernel 5: finalize — triplet loss + variance + MMD mean -> out[0]
// ---------------------------------------------------------------------------
__global__ __launch_bounds__(64) void finalize_kernel(
    const float* __restrict__ dist, const float* __restrict__ mmdpart,
    float* __restrict__ out) {
  int lane = threadIdx.x;
  float lv_po = 0.f;
  float dg[5];
#pragma unroll
  for (int g = 0; g < 5; ++g) dg[g] = 0.f;
  if (lane < 8) {
    const float* dr = dist + lane * 15;
    float dn[10];
#pragma unroll
    for (int g = 0; g < 5; ++g) dg[g] = dr[g];
#pragma unroll
    for (int k = 0; k < 10; ++k) dn[k] = dr[5 + k];
    float s1 = 0.f, s2 = 0.f;
    int nz = 0;
#pragma unroll
    for (int g = 0; g < 5; ++g) {
#pragma unroll
      for (int k = 0; k < 5; ++k) {
        float v2 = dg[g] + 1.0f - dn[k];
        if (v2 > 0.f) { s1 += v2; ++nz; }
      }
#pragma unroll
      for (int k = 5; k < 10; ++k) {
        float v2 = dg[g] + 1.0f - dn[k];
        if (v2 > 0.f) { s2 += v2; ++nz; }
      }
    }
    float only_pos = (dg[0] + dg[1] + dg[2] + dg[3] + dg[4]) * 0.002f;
    float lv = (s1 * 0.7f + s2 * 0.3f) / (float)(nz + 1);
    lv_po = lv + only_pos;
  }
  float tl = wred_sum(lv_po);
  tl = __shfl(tl, 0);

  // two-pass ddof=1 variance over the 40 dg values
  float psum = dg[0] + dg[1] + dg[2] + dg[3] + dg[4];
  float tsum = wred_sum(psum);
  float mean = __shfl(tsum, 0) * (1.f / 40.f);
  float pdev = 0.f;
  if (lane < 8) {
#pragma unroll
    for (int g = 0; g < 5; ++g) {
      float dd = dg[g] - mean;
      pdev = fmaf(dd, dd, pdev);
    }
  }
  float tdev = wred_sum(pdev);
  tdev = __shfl(tdev, 0);

  float msum = 0.f;
  for (int k2 = lane; k2 < 121; k2 += 64) msum += mmdpart[k2];
  float mt = wred_sum(msum);

  if (lane == 0) {
    float total_loss = tl * (1.f / 8.f);
    float var_g = (tdev / 39.f) * 0.1f;
    float mmd = mt * (1.f / 7744.f);
    out[0] = total_loss + mmd + var_g;
  }
}

__global__ __launch_bounds__(64) void zero_out_kernel(float* __restrict__ out,
                                                      int n) {
  int i = blockIdx.x * 64 + threadIdx.x;
  if (i < n) out[i] = 0.f;
}

// ---------------------------------------------------------------------------
extern "C" void kernel_launch(void* const* d_in, const int* in_sizes, int n_in,
                              void* d_out, int out_size, void* d_ws,
                              size_t ws_size, hipStream_t stream) {
  const float* data = (const float*)d_in[0];
  const int* lens = (const int*)d_in[1];
  float* out = (float*)d_out;
  char* ws = (char*)d_ws;

  const size_t HDR = 131072;  // dist/bwpart/mmdpart/l2buf region
  const size_t per_pair = (size_t)T_ * T_ * sizeof(float);  // 1 MB row-major

  // Strict workspace guard: never touch bytes beyond ws_size.
  if (ws_size < HDR + per_pair) {
    zero_out_kernel<<<dim3((out_size + 63) / 64), 64, 0, stream>>>(out,
                                                                   out_size);
    return;
  }

  float* dist = (float*)(ws + 0);        // 120 floats
  float* bwpart = (float*)(ws + 1024);   // 253 floats
  float* mmdpart = (float*)(ws + 3072);  // 121 floats
  float* l2buf = (float*)(ws + 4096);    // 22*22*64 floats = 123904 B
  float* dsk = (float*)(ws + HDR);

  size_t avail = ws_size - HDR;
  int PC = (int)(avail / per_pair);
  if (PC > NPAIR) PC = NPAIR;

  for (int p0 = 0; p0 < NPAIR; p0 += PC) {
    int pc = (NPAIR - p0) < PC ? (NPAIR - p0) : PC;
    gemm_kernel<<<dim3(64, pc), 256, 0, stream>>>(data, dsk, p0);
    dtw_kernel<<<dim3(pc), 64, 0, stream>>>(dsk, lens, dist, p0);
  }
  mmd_l2_kernel<<<dim3(253), 64, 0, stream>>>(data, l2buf, bwpart);
  mmd_k_kernel<<<dim3(121), 64, 0, stream>>>(l2buf, bwpart, mmdpart);
  finalize_kernel<<<dim3(1), 64, 0, stream>>>(dist, mmdpart, out);
}

// Round 5
// 361.556 us; speedup vs baseline: 1.3127x; 1.3127x over previous
//
#include <hip/hip_runtime.h>
#include <hip/hip_bf16.h>
#include <cstdint>
#include <cstddef>

#define T_ 512
#define DF 64
#define NPAIR 120
#define STEPW 16
#define NEGS (-(1 << 26))

// softmin constants: exp((m-x)/g) = exp2((m-x)*log2(e)/g); g*ln(2)
#define C1_ 0.28853900817779268f   // log2(e)/5
#define C2D 3.4657359027997265     // 5*ln(2), double

__device__ __forceinline__ float wred_sum(float v) {
#pragma unroll
  for (int o = 32; o > 0; o >>= 1) v += __shfl_down(v, o);
  return v;  // lane 0 holds the total
}

__device__ __forceinline__ int dexp(double x) {
  // biased-exponent field - 1023; 0.0 -> -1023 (safe "very small" marker)
  return (int)((__double_as_longlong(x) >> 52) & 0x7ff) - 1023;
}

// ---------------------------------------------------------------------------
// Kernel 1: pairwise sq-dist GEMM; epilogue stores W = exp(-D/gamma) (fp32).
// ---------------------------------------------------------------------------
__global__ __launch_bounds__(256) void gemm_kernel(
    const float* __restrict__ data, float* __restrict__ wbuf, int pair0) {
  __shared__ float Xs[64][65];
  __shared__ float Ys[64][65];
  __shared__ float nrmx[64];
  __shared__ float nrmy[64];

  const int tile = blockIdx.x;   // 0..63 = (bi<<3)|bj
  const int pc = blockIdx.y;     // pair within chunk
  const int p = pair0 + pc;
  const int w = p / 15;
  const int o = p - w * 15;
  const int aidx = w * STEPW;
  const int oidx = aidx + 1 + o;
  const int i0 = (tile >> 3) << 6;
  const int j0 = (tile & 7) << 6;
  const int tid = threadIdx.x;

  const float* Xg = data + (size_t)aidx * (T_ * DF);
  const float* Yg = data + (size_t)oidx * (T_ * DF);

#pragma unroll
  for (int l = 0; l < 4; ++l) {
    int idx = tid + l * 256;  // 0..1023
    int r = idx >> 4;
    int c = idx & 15;
    float4 xv = reinterpret_cast<const float4*>(Xg + (size_t)(i0 + r) * DF)[c];
    float4 yv = reinterpret_cast<const float4*>(Yg + (size_t)(j0 + r) * DF)[c];
    Xs[r][4 * c + 0] = xv.x; Xs[r][4 * c + 1] = xv.y;
    Xs[r][4 * c + 2] = xv.z; Xs[r][4 * c + 3] = xv.w;
    Ys[r][4 * c + 0] = yv.x; Ys[r][4 * c + 1] = yv.y;
    Ys[r][4 * c + 2] = yv.z; Ys[r][4 * c + 3] = yv.w;
  }
  __syncthreads();

  if (tid < 128) {
    int r = tid & 63;
    const float* row = (tid < 64) ? Xs[r] : Ys[r];
    float s = 0.f;
#pragma unroll
    for (int k = 0; k < 64; ++k) s = fmaf(row[k], row[k], s);
    if (tid < 64) nrmx[r] = s; else nrmy[r] = s;
  }
  __syncthreads();

  const int tx = tid & 15;
  const int ty = tid >> 4;
  float acc[4][4];
#pragma unroll
  for (int a = 0; a < 4; ++a)
#pragma unroll
    for (int b = 0; b < 4; ++b) acc[a][b] = 0.f;

#pragma unroll 4
  for (int k = 0; k < 64; ++k) {
    float xr[4], yr[4];
#pragma unroll
    for (int a = 0; a < 4; ++a) xr[a] = Xs[ty * 4 + a][k];
#pragma unroll
    for (int b = 0; b < 4; ++b) yr[b] = Ys[tx * 4 + b][k];
#pragma unroll
    for (int a = 0; a < 4; ++a)
#pragma unroll
      for (int b = 0; b < 4; ++b) acc[a][b] = fmaf(xr[a], yr[b], acc[a][b]);
  }

  // epilogue: W = exp2(-d * log2e/gamma), coalesced float4 stores
  float* Wp = wbuf + (size_t)pc * (T_ * T_) + (size_t)i0 * T_ + j0;
#pragma unroll
  for (int a = 0; a < 4; ++a) {
    int ii = ty * 4 + a;
    float nx = nrmx[ii];
    float4 v;
    v.x = __builtin_exp2f(-(nx + nrmy[tx * 4 + 0] - 2.f * acc[a][0]) * C1_);
    v.y = __builtin_exp2f(-(nx + nrmy[tx * 4 + 1] - 2.f * acc[a][1]) * C1_);
    v.z = __builtin_exp2f(-(nx + nrmy[tx * 4 + 2] - 2.f * acc[a][2]) * C1_);
    v.w = __builtin_exp2f(-(nx + nrmy[tx * 4 + 3] - 2.f * acc[a][3]) * C1_);
    *reinterpret_cast<float4*>(Wp + (size_t)ii * T_ + tx * 4) = v;
  }
}

// ---------------------------------------------------------------------------
// Kernel 2: softDTW in EXP-DOMAIN, fp64 mantissa + per-lane block exponent.
// One wave per pair, zero barriers. Lane l owns cols [8l,8l+8), staggered
// 2 rows/lane so the (value,scale) boundary shuffle has one full step of
// slack.  E[i][j] = w[i][j]*(E_left + E_up + E_diag);  R = -g*ln(E).
// Intra-lane spread ~37-70 bits/col * 8 cols fits fp64's 1074-binade
// window (fp32's 150 did NOT -> round-4 NaN).
// ---------------------------------------------------------------------------
__global__ __launch_bounds__(64) void dtw_kernel(
    const float* __restrict__ Wm, const int* __restrict__ lens,
    float* __restrict__ dist, int pair0) {
  const int pc = blockIdx.x;
  const int p = pair0 + pc;
  const int w = p / 15;
  const int o = p - w * 15;
  const int lx = lens[w * STEPW];
  const int ly = lens[w * STEPW + 1 + o];
  const int l = threadIdx.x;
  const int imax = lx - 1;
  const int jt = ly - 1;
  const int lt = jt >> 3, ct = jt & 7;
  const int nmax = imax + 2 * lt;
  const float invl = 1.f / (float)(lx + ly);

  const float* wp = Wm + (size_t)pc * (T_ * T_) + (l << 3);

  // previous-row E (fp64 mantissas, one shared block exponent S)
  double e0 = 0., e1 = 0., e2 = 0., e3 = 0.;
  double e4 = 0., e5 = 0., e6 = 0., e7 = 0.;
  int S = NEGS;

  // boundary shuffle pipeline (value+scale pairs, 2-step slack)
  double pv = 0.;  int ps = NEGS;
  double bl1v = 0., bl2v = 0.;  int bl1S = NEGS, bl2S = NEGS;

  // W-row prefetch, 4 deep, named register stages (A=row i ... D=row i+3)
  float4 A0 = {}, A1 = {}, B0 = {}, B1 = {};
  float4 C0 = {}, C1 = {}, D0 = {}, D1 = {};
  {
    int r;
    r = 0 - 2 * l;
    if (r >= 0) { A0 = *reinterpret_cast<const float4*>(wp + (size_t)r * T_);
                  A1 = *reinterpret_cast<const float4*>(wp + (size_t)r * T_ + 4); }
    r = 1 - 2 * l;
    if (r >= 0) { B0 = *reinterpret_cast<const float4*>(wp + (size_t)r * T_);
                  B1 = *reinterpret_cast<const float4*>(wp + (size_t)r * T_ + 4); }
    r = 2 - 2 * l;
    if (r >= 0) { C0 = *reinterpret_cast<const float4*>(wp + (size_t)r * T_);
                  C1 = *reinterpret_cast<const float4*>(wp + (size_t)r * T_ + 4); }
    r = 3 - 2 * l;
    if (r >= 0) { D0 = *reinterpret_cast<const float4*>(wp + (size_t)r * T_);
                  D1 = *reinterpret_cast<const float4*>(wp + (size_t)r * T_ + 4); }
  }

  double out_v = 1.; int out_S = 0;

  for (int n = 0; n <= nmax; ++n) {
    // snapshot neighbor (e7, S) for consumption one step later
    double nv = __shfl_up(e7, 1);
    int ns = __shfl_up(S, 1);
    bl2v = bl1v; bl2S = bl1S;
    bl1v = pv;   bl1S = ps;
    const int i = n - 2 * l;
    if (l == 0) {
      bl1v = 0.; bl1S = NEGS;
      bl2v = (i == 0) ? 1. : 0.;
      bl2S = (i == 0) ? 0 : NEGS;
    }
    // prefetch row i+4
    const int rpf = i + 4;
    float4 P0 = {}, P1 = {};
    if ((unsigned)rpf < (unsigned)T_) {
      P0 = *reinterpret_cast<const float4*>(wp + (size_t)rpf * T_);
      P1 = *reinterpret_cast<const float4*>(wp + (size_t)rpf * T_ + 4);
    }
    if ((unsigned)i <= (unsigned)imax) {
      // new scale = max over candidate input scales (no overflow possible:
      // every aligned operand ends up <= ~2)
      double sum = ((e0 + e1) + (e2 + e3)) + ((e4 + e5) + (e6 + e7));
      int cS = S + dexp(sum);
      int SL = bl1S + dexp(bl1v);
      int SD = bl2S + dexp(bl2v);
      int N = max(cS, max(SL, SD));
      const int dS = S - N;
      double u0 = ldexp(e0, dS), u1 = ldexp(e1, dS);
      double u2 = ldexp(e2, dS), u3 = ldexp(e3, dS);
      double u4 = ldexp(e4, dS), u5 = ldexp(e5, dS);
      double u6 = ldexp(e6, dS), u7 = ldexp(e7, dS);
      double L = ldexp(bl1v, bl1S - N);
      double G = ldexp(bl2v, bl2S - N);
      const double W0 = (double)A0.x, W1 = (double)A0.y;
      const double W2 = (double)A0.z, W3 = (double)A0.w;
      const double W4 = (double)A1.x, W5 = (double)A1.y;
      const double W6 = (double)A1.z, W7 = (double)A1.w;
      // off-chain partial terms (up + diag)
      double q0 = W0 * ((L + G) + u0);
      double q1 = W1 * (u1 + u0);
      double q2 = W2 * (u2 + u1);
      double q3 = W3 * (u3 + u2);
      double q4 = W4 * (u4 + u3);
      double q5 = W5 * (u5 + u4);
      double q6 = W6 * (u6 + u5);
      double q7 = W7 * (u7 + u6);
      // the serial chain: 7 fp64 FMAs
      e0 = q0;
      e1 = fma(W1, e0, q1);
      e2 = fma(W2, e1, q2);
      e3 = fma(W3, e2, q3);
      e4 = fma(W4, e3, q4);
      e5 = fma(W5, e4, q5);
      e6 = fma(W6, e5, q6);
      e7 = fma(W7, e6, q7);
      S = N;
      if (n == nmax && l == lt) {
        out_v = (ct == 0) ? e0 : (ct == 1) ? e1 : (ct == 2) ? e2
              : (ct == 3) ? e3 : (ct == 4) ? e4 : (ct == 5) ? e5
              : (ct == 6) ? e6 : e7;
        out_S = N;
      }
    }
    pv = nv; ps = ns;
    A0 = B0; A1 = B1; B0 = C0; B1 = C1; C0 = D0; C1 = D1; D0 = P0; D1 = P1;
  }

  if (l == lt) {
    // R = -gamma*ln(E) = -gamma*ln2*(log2(v) + S)
    double vv = (out_v > 0.) ? out_v : 1e-300;  // belt-and-braces, never binds
    double r = -C2D * (log2(vv) + (double)out_S);
    dist[p] = (float)(r * (double)invl);
  }
}

// ---------------------------------------------------------------------------
// Kernel 3: MMD pairwise per-feature L2 (upper triangle, mirrored)
// ---------------------------------------------------------------------------
__global__ __launch_bounds__(64) void mmd_l2_kernel(
    const float* __restrict__ data, float* __restrict__ l2buf,
    float* __restrict__ bwpart) {
  int b = blockIdx.x;  // 0..252 upper-tri (incl diag) index
  int u = 0, rem = b;
  while (rem >= 22 - u) { rem -= 22 - u; ++u; }
  int v = u + rem;
  int f = threadIdx.x;
  float s = 0.f;
  if (u != v) {
    int iu = u < 11 ? u : u + 5;
    int iv = v < 11 ? v : v + 5;
    const float* A = data + (size_t)iu * (T_ * DF) + f;
    const float* B = data + (size_t)iv * (T_ * DF) + f;
#pragma unroll 8
    for (int t = 0; t < T_; ++t) {
      float dd = A[(size_t)t * DF] - B[(size_t)t * DF];
      s = fmaf(dd, dd, s);
    }
  }
  l2buf[(size_t)(u * 22 + v) * 64 + f] = s;
  l2buf[(size_t)(v * 22 + u) * 64 + f] = s;
  float tot = wred_sum(s);
  if (f == 0) bwpart[b] = 2.f * tot;  // diag contributes exactly 0
}

// ---------------------------------------------------------------------------
// Kernel 4: MMD kernel sums per (a,c) of the 11x11 grid
// ---------------------------------------------------------------------------
__global__ __launch_bounds__(64) void mmd_k_kernel(
    const float* __restrict__ l2buf, const float* __restrict__ bwpart,
    float* __restrict__ mmdpart) {
  int b = blockIdx.x;  // 0..120
  int a = b / 11, c = b - a * 11;
  int f = threadIdx.x;
  float bs = 0.f;
  for (int k2 = f; k2 < 253; k2 += 64) bs += bwpart[k2];
  bs = wred_sum(bs);
  float bw = __shfl(bs, 0) * (1.f / (462.f * 4.f));  // /(n^2-n)/KMUL^(KNUM//2)
  float xx = l2buf[(size_t)(a * 22 + c) * 64 + f];
  float yy = l2buf[(size_t)((11 + a) * 22 + (11 + c)) * 64 + f];
  float xy = l2buf[(size_t)(a * 22 + (11 + c)) * 64 + f];
  float yx = l2buf[(size_t)((11 + a) * 22 + c) * 64 + f];
  float term = 0.f;
  float ib = 1.f / bw;
#pragma unroll
  for (int i = 0; i < 5; ++i) {
    term += expf(-xx * ib) + expf(-yy * ib) - expf(-xy * ib) - expf(-yx * ib);
    ib *= 0.5f;
  }
  float tt = wred_sum(term);
  if (f == 0) mmdpart[b] = tt;
}

// ---------------------------------------------------------------------------
// Kernel 5: finalize — triplet loss + variance + MMD mean -> out[0]
// ---------------------------------------------------------------------------
__global__ __launch_bounds__(64) void finalize_kernel(
    const float* __restrict__ dist, const float* __restrict__ mmdpart,
    float* __restrict__ out) {
  int lane = threadIdx.x;
  float lv_po = 0.f;
  float dg[5];
#pragma unroll
  for (int g = 0; g < 5; ++g) dg[g] = 0.f;
  if (lane < 8) {
    const float* dr = dist + lane * 15;
    float dn[10];
#pragma unroll
    for (int g = 0; g < 5; ++g) dg[g] = dr[g];
#pragma unroll
    for (int k = 0; k < 10; ++k) dn[k] = dr[5 + k];
    float s1 = 0.f, s2 = 0.f;
    int nz = 0;
#pragma unroll
    for (int g = 0; g < 5; ++g) {
#pragma unroll
      for (int k = 0; k < 5; ++k) {
        float v2 = dg[g] + 1.0f - dn[k];
        if (v2 > 0.f) { s1 += v2; ++nz; }
      }
#pragma unroll
      for (int k = 5; k < 10; ++k) {
        float v2 = dg[g] + 1.0f - dn[k];
        if (v2 > 0.f) { s2 += v2; ++nz; }
      }
    }
    float only_pos = (dg[0] + dg[1] + dg[2] + dg[3] + dg[4]) * 0.002f;
    float lv = (s1 * 0.7f + s2 * 0.3f) / (float)(nz + 1);
    lv_po = lv + only_pos;
  }
  float tl = wred_sum(lv_po);
  tl = __shfl(tl, 0);

  // two-pass ddof=1 variance over the 40 dg values
  float psum = dg[0] + dg[1] + dg[2] + dg[3] + dg[4];
  float tsum = wred_sum(psum);
  float mean = __shfl(tsum, 0) * (1.f / 40.f);
  float pdev = 0.f;
  if (lane < 8) {
#pragma unroll
    for (int g = 0; g < 5; ++g) {
      float dd = dg[g] - mean;
      pdev = fmaf(dd, dd, pdev);
    }
  }
  float tdev = wred_sum(pdev);
  tdev = __shfl(tdev, 0);

  float msum = 0.f;
  for (int k2 = lane; k2 < 121; k2 += 64) msum += mmdpart[k2];
  float mt = wred_sum(msum);

  if (lane == 0) {
    float total_loss = tl * (1.f / 8.f);
    float var_g = (tdev / 39.f) * 0.1f;
    float mmd = mt * (1.f / 7744.f);
    out[0] = total_loss + mmd + var_g;
  }
}

__global__ __launch_bounds__(64) void zero_out_kernel(float* __restrict__ out,
                                                      int n) {
  int i = blockIdx.x * 64 + threadIdx.x;
  if (i < n) out[i] = 0.f;
}

// ---------------------------------------------------------------------------
extern "C" void kernel_launch(void* const* d_in, const int* in_sizes, int n_in,
                              void* d_out, int out_size, void* d_ws,
                              size_t ws_size, hipStream_t stream) {
  const float* data = (const float*)d_in[0];
  const int* lens = (const int*)d_in[1];
  float* out = (float*)d_out;
  char* ws = (char*)d_ws;

  const size_t HDR = 131072;  // dist/bwpart/mmdpart/l2buf region
  const size_t per_pair = (size_t)T_ * T_ * sizeof(float);  // 1 MB

  // Strict workspace guard: never touch bytes beyond ws_size.
  if (ws_size < HDR + per_pair) {
    zero_out_kernel<<<dim3((out_size + 63) / 64), 64, 0, stream>>>(out,
                                                                   out_size);
    return;
  }

  float* dist = (float*)(ws + 0);        // 120 floats
  float* bwpart = (float*)(ws + 1024);   // 253 floats
  float* mmdpart = (float*)(ws + 3072);  // 121 floats
  float* l2buf = (float*)(ws + 4096);    // 22*22*64 floats = 123904 B
  float* wbuf = (float*)(ws + HDR);

  size_t avail = ws_size - HDR;
  int PC = (int)(avail / per_pair);
  if (PC > NPAIR) PC = NPAIR;

  for (int p0 = 0; p0 < NPAIR; p0 += PC) {
    int pc = (NPAIR - p0) < PC ? (NPAIR - p0) : PC;
    gemm_kernel<<<dim3(64, pc), 256, 0, stream>>>(data, wbuf, p0);
    dtw_kernel<<<dim3(pc), 64, 0, stream>>>(wbuf, lens, dist, p0);
  }
  mmd_l2_kernel<<<dim3(253), 64, 0, stream>>>(data, l2buf, bwpart);
  mmd_k_kernel<<<dim3(121), 64, 0, stream>>>(l2buf, bwpart, mmdpart);
  finalize_kernel<<<dim3(1), 64, 0, stream>>>(dist, mmdpart, out);
}

// Round 7
// 327.992 us; speedup vs baseline: 1.4470x; 1.1023x over previous
//
#include <hip/hip_runtime.h>
#include <hip/hip_bf16.h>
#include <cstdint>
#include <cstddef>

#define T_ 512
#define DF 64
#define NPAIR 120
#define STEPW 16
#define NEGS (-(1 << 26))

// softmin constants: exp((m-x)/g) = exp2((m-x)*log2(e)/g); g*ln(2)
#define C1_ 0.28853900817779268f   // log2(e)/5
#define C2D 3.4657359027997265     // 5*ln(2), double

__device__ __forceinline__ float wred_sum(float v) {
#pragma unroll
  for (int o = 32; o > 0; o >>= 1) v += __shfl_down(v, o);
  return v;  // lane 0 holds the total
}

__device__ __forceinline__ int dexp(double x) {
  // biased-exponent field - 1023; 0.0 -> -1023 (safe "very small" marker)
  return (int)((__double_as_longlong(x) >> 52) & 0x7ff) - 1023;
}

// ---------------------------------------------------------------------------
// Kernel 1: pairwise sq-dist GEMM; epilogue stores W = exp(-D/gamma) (fp32).
// ---------------------------------------------------------------------------
__global__ __launch_bounds__(256) void gemm_kernel(
    const float* __restrict__ data, float* __restrict__ wbuf, int pair0) {
  __shared__ float Xs[64][65];
  __shared__ float Ys[64][65];
  __shared__ float nrmx[64];
  __shared__ float nrmy[64];

  const int tile = blockIdx.x;   // 0..63 = (bi<<3)|bj
  const int pc = blockIdx.y;     // pair within chunk
  const int p = pair0 + pc;
  const int w = p / 15;
  const int o = p - w * 15;
  const int aidx = w * STEPW;
  const int oidx = aidx + 1 + o;
  const int i0 = (tile >> 3) << 6;
  const int j0 = (tile & 7) << 6;
  const int tid = threadIdx.x;

  const float* Xg = data + (size_t)aidx * (T_ * DF);
  const float* Yg = data + (size_t)oidx * (T_ * DF);

#pragma unroll
  for (int l = 0; l < 4; ++l) {
    int idx = tid + l * 256;  // 0..1023
    int r = idx >> 4;
    int c = idx & 15;
    float4 xv = reinterpret_cast<const float4*>(Xg + (size_t)(i0 + r) * DF)[c];
    float4 yv = reinterpret_cast<const float4*>(Yg + (size_t)(j0 + r) * DF)[c];
    Xs[r][4 * c + 0] = xv.x; Xs[r][4 * c + 1] = xv.y;
    Xs[r][4 * c + 2] = xv.z; Xs[r][4 * c + 3] = xv.w;
    Ys[r][4 * c + 0] = yv.x; Ys[r][4 * c + 1] = yv.y;
    Ys[r][4 * c + 2] = yv.z; Ys[r][4 * c + 3] = yv.w;
  }
  __syncthreads();

  if (tid < 128) {
    int r = tid & 63;
    const float* row = (tid < 64) ? Xs[r] : Ys[r];
    float s = 0.f;
#pragma unroll
    for (int k = 0; k < 64; ++k) s = fmaf(row[k], row[k], s);
    if (tid < 64) nrmx[r] = s; else nrmy[r] = s;
  }
  __syncthreads();

  const int tx = tid & 15;
  const int ty = tid >> 4;
  float acc[4][4];
#pragma unroll
  for (int a = 0; a < 4; ++a)
#pragma unroll
    for (int b = 0; b < 4; ++b) acc[a][b] = 0.f;

#pragma unroll 4
  for (int k = 0; k < 64; ++k) {
    float xr[4], yr[4];
#pragma unroll
    for (int a = 0; a < 4; ++a) xr[a] = Xs[ty * 4 + a][k];
#pragma unroll
    for (int b = 0; b < 4; ++b) yr[b] = Ys[tx * 4 + b][k];
#pragma unroll
    for (int a = 0; a < 4; ++a)
#pragma unroll
      for (int b = 0; b < 4; ++b) acc[a][b] = fmaf(xr[a], yr[b], acc[a][b]);
  }

  // epilogue: W = exp2(-d * log2e/gamma), coalesced float4 stores
  float* Wp = wbuf + (size_t)pc * (T_ * T_) + (size_t)i0 * T_ + j0;
#pragma unroll
  for (int a = 0; a < 4; ++a) {
    int ii = ty * 4 + a;
    float nx = nrmx[ii];
    float4 v;
    v.x = __builtin_exp2f(-(nx + nrmy[tx * 4 + 0] - 2.f * acc[a][0]) * C1_);
    v.y = __builtin_exp2f(-(nx + nrmy[tx * 4 + 1] - 2.f * acc[a][1]) * C1_);
    v.z = __builtin_exp2f(-(nx + nrmy[tx * 4 + 2] - 2.f * acc[a][2]) * C1_);
    v.w = __builtin_exp2f(-(nx + nrmy[tx * 4 + 3] - 2.f * acc[a][3]) * C1_);
    *reinterpret_cast<float4*>(Wp + (size_t)ii * T_ + tx * 4) = v;
  }
}

// ---------------------------------------------------------------------------
// Kernel 2: softDTW in EXP-DOMAIN, fp64 mantissa + per-lane block exponent.
// One wave per pair, zero barriers. Lane l owns cols [8l,8l+8), staggered
// 2 rows/lane.  E[i][j] = w[i][j]*(E_left + E_up + E_diag);  R = -g*ln(E).
// Scale N = S + dexp(sum of all 8 cells): sum bounds the max for ANY
// magnitude ordering (round-6's "e0 is largest" was wrong: E is unimodal
// in j with max near j==i, so rows below the window grow toward e7 ->
// overflow -> Inf -> 0*Inf NaN with flushed fp32 W).
// MODULO-SCHEDULED prefetch: 8 named buffer slots, sub-step t consumes
// slot t then reloads it 8 rows ahead -> no register rotation, no per-step
// vmcnt(0) drain (round-5's rotation collapsed prefetch depth to ~1 and
// exposed ~900 cy of L2/L3 latency per step).
// ---------------------------------------------------------------------------
__global__ __launch_bounds__(64) void dtw_kernel(
    const float* __restrict__ Wm, const int* __restrict__ lens,
    float* __restrict__ dist, int pair0) {
  const int pc = blockIdx.x;
  const int p = pair0 + pc;
  const int w = p / 15;
  const int o = p - w * 15;
  const int lx = lens[w * STEPW];
  const int ly = lens[w * STEPW + 1 + o];
  const int l = threadIdx.x;
  const int imax = lx - 1;
  const int jt = ly - 1;
  const int lt = jt >> 3, ct = jt & 7;
  const int nmax = imax + 2 * lt;
  const float invl = 1.f / (float)(lx + ly);

  const float* wp = Wm + (size_t)pc * (T_ * T_) + (l << 3);

  // previous-row E (fp64 mantissas, one shared block exponent S)
  double e0 = 0., e1 = 0., e2 = 0., e3 = 0.;
  double e4 = 0., e5 = 0., e6 = 0., e7 = 0.;
  int S = NEGS;

  // boundary shuffle pipeline (value+scale pairs, 2-step slack)
  double pv = 0.;  int ps = NEGS;
  double bl1v = 0., bl2v = 0.;  int bl1S = NEGS, bl2S = NEGS;

  // 8 named W buffer slots; slot t holds row (n - 2l) for sub-steps n%8 == t
  float4 Wa0 = {}, Wa1 = {}, Wb0 = {}, Wb1 = {};
  float4 Wc0 = {}, Wc1 = {}, Wd0 = {}, Wd1 = {};
  float4 We0 = {}, We1 = {}, Wf0 = {}, Wf1 = {};
  float4 Wg0 = {}, Wg1 = {}, Wh0 = {}, Wh1 = {};

#define LDW(B0, B1, R)                                                   \
  {                                                                      \
    const int r_ = (R);                                                  \
    if ((unsigned)r_ < (unsigned)T_) {                                   \
      B0 = *reinterpret_cast<const float4*>(wp + (size_t)r_ * T_);       \
      B1 = *reinterpret_cast<const float4*>(wp + (size_t)r_ * T_ + 4);   \
    }                                                                    \
  }

  // prologue fill
  LDW(Wa0, Wa1, 0 - 2 * l); LDW(Wb0, Wb1, 1 - 2 * l);
  LDW(Wc0, Wc1, 2 - 2 * l); LDW(Wd0, Wd1, 3 - 2 * l);
  LDW(We0, We1, 4 - 2 * l); LDW(Wf0, Wf1, 5 - 2 * l);
  LDW(Wg0, Wg1, 6 - 2 * l); LDW(Wh0, Wh1, 7 - 2 * l);

  double out_v = 1.; int out_S = 0;

#define STEP(NN, B0, B1)                                                   \
  {                                                                        \
    const int n_ = (NN);                                                   \
    double nv = __shfl_up(e7, 1);                                          \
    int ns = __shfl_up(S, 1);                                              \
    bl2v = bl1v; bl2S = bl1S;                                              \
    bl1v = pv;   bl1S = ps;                                                \
    const int i = n_ - 2 * l;                                              \
    if (l == 0) {                                                          \
      bl1v = 0.; bl1S = NEGS;                                              \
      bl2v = (i == 0) ? 1. : 0.;                                           \
      bl2S = (i == 0) ? 0 : NEGS;                                          \
    }                                                                      \
    if ((unsigned)i <= (unsigned)imax) {                                   \
      double sum = ((e0 + e1) + (e2 + e3)) + ((e4 + e5) + (e6 + e7));      \
      int N = max(S + dexp(sum),                                           \
                  max(bl1S + dexp(bl1v), bl2S + dexp(bl2v)));              \
      const int dS = S - N;                                                \
      double u0 = ldexp(e0, dS), u1 = ldexp(e1, dS);                       \
      double u2 = ldexp(e2, dS), u3 = ldexp(e3, dS);                       \
      double u4 = ldexp(e4, dS), u5 = ldexp(e5, dS);                       \
      double u6 = ldexp(e6, dS), u7 = ldexp(e7, dS);                       \
      double L = ldexp(bl1v, bl1S - N);                                    \
      double G = ldexp(bl2v, bl2S - N);                                    \
      const double W0 = (double)B0.x, W1 = (double)B0.y;                   \
      const double W2 = (double)B0.z, W3 = (double)B0.w;                   \
      const double W4 = (double)B1.x, W5 = (double)B1.y;                   \
      const double W6 = (double)B1.z, W7 = (double)B1.w;                   \
      double q0 = W0 * ((L + G) + u0);                                     \
      double q1 = W1 * (u1 + u0);                                          \
      double q2 = W2 * (u2 + u1);                                          \
      double q3 = W3 * (u3 + u2);                                          \
      double q4 = W4 * (u4 + u3);                                          \
      double q5 = W5 * (u5 + u4);                                          \
      double q6 = W6 * (u6 + u5);                                          \
      double q7 = W7 * (u7 + u6);                                          \
      e0 = q0;                                                             \
      e1 = fma(W1, e0, q1);                                                \
      e2 = fma(W2, e1, q2);                                                \
      e3 = fma(W3, e2, q3);                                                \
      e4 = fma(W4, e3, q4);                                                \
      e5 = fma(W5, e4, q5);                                                \
      e6 = fma(W6, e5, q6);                                                \
      e7 = fma(W7, e6, q7);                                                \
      S = N;                                                               \
      if (n_ == nmax && l == lt) {                                         \
        out_v = (ct == 0) ? e0 : (ct == 1) ? e1 : (ct == 2) ? e2           \
              : (ct == 3) ? e3 : (ct == 4) ? e4 : (ct == 5) ? e5           \
              : (ct == 6) ? e6 : e7;                                       \
        out_S = N;                                                         \
      }                                                                    \
    }                                                                      \
    pv = nv; ps = ns;                                                      \
    LDW(B0, B1, i + 8);  /* reload same slot, consumed 8 steps later */    \
  }

  const int nend = (nmax + 8) & ~7;  // covers n = 0..nmax
  for (int nb = 0; nb < nend; nb += 8) {
    STEP(nb + 0, Wa0, Wa1);
    STEP(nb + 1, Wb0, Wb1);
    STEP(nb + 2, Wc0, Wc1);
    STEP(nb + 3, Wd0, Wd1);
    STEP(nb + 4, We0, We1);
    STEP(nb + 5, Wf0, Wf1);
    STEP(nb + 6, Wg0, Wg1);
    STEP(nb + 7, Wh0, Wh1);
  }

  if (l == lt) {
    // R = -gamma*ln(E) = -gamma*ln2*(log2(v) + S)
    double vv = (out_v > 0.) ? out_v : 1e-300;  // belt-and-braces
    double r = -C2D * (log2(vv) + (double)out_S);
    dist[p] = (float)(r * (double)invl);
  }
}

// ---------------------------------------------------------------------------
// Kernel 3: MMD pairwise per-feature L2 (upper triangle, mirrored)
// ---------------------------------------------------------------------------
__global__ __launch_bounds__(64) void mmd_l2_kernel(
    const float* __restrict__ data, float* __restrict__ l2buf,
    float* __restrict__ bwpart) {
  int b = blockIdx.x;  // 0..252 upper-tri (incl diag) index
  int u = 0, rem = b;
  while (rem >= 22 - u) { rem -= 22 - u; ++u; }
  int v = u + rem;
  int f = threadIdx.x;
  float s = 0.f;
  if (u != v) {
    int iu = u < 11 ? u : u + 5;
    int iv = v < 11 ? v : v + 5;
    const float* A = data + (size_t)iu * (T_ * DF) + f;
    const float* B = data + (size_t)iv * (T_ * DF) + f;
#pragma unroll 8
    for (int t = 0; t < T_; ++t) {
      float dd = A[(size_t)t * DF] - B[(size_t)t * DF];
      s = fmaf(dd, dd, s);
    }
  }
  l2buf[(size_t)(u * 22 + v) * 64 + f] = s;
  l2buf[(size_t)(v * 22 + u) * 64 + f] = s;
  float tot = wred_sum(s);
  if (f == 0) bwpart[b] = 2.f * tot;  // diag contributes exactly 0
}

// ---------------------------------------------------------------------------
// Kernel 4: MMD kernel sums per (a,c) of the 11x11 grid
// ---------------------------------------------------------------------------
__global__ __launch_bounds__(64) void mmd_k_kernel(
    const float* __restrict__ l2buf, const float* __restrict__ bwpart,
    float* __restrict__ mmdpart) {
  int b = blockIdx.x;  // 0..120
  int a = b / 11, c = b - a * 11;
  int f = threadIdx.x;
  float bs = 0.f;
  for (int k2 = f; k2 < 253; k2 += 64) bs += bwpart[k2];
  bs = wred_sum(bs);
  float bw = __shfl(bs, 0) * (1.f / (462.f * 4.f));  // /(n^2-n)/KMUL^(KNUM//2)
  float xx = l2buf[(size_t)(a * 22 + c) * 64 + f];
  float yy = l2buf[(size_t)((11 + a) * 22 + (11 + c)) * 64 + f];
  float xy = l2buf[(size_t)(a * 22 + (11 + c)) * 64 + f];
  float yx = l2buf[(size_t)((11 + a) * 22 + c) * 64 + f];
  float term = 0.f;
  float ib = 1.f / bw;
#pragma unroll
  for (int i = 0; i < 5; ++i) {
    term += expf(-xx * ib) + expf(-yy * ib) - expf(-xy * ib) - expf(-yx * ib);
    ib *= 0.5f;
  }
  float tt = wred_sum(term);
  if (f == 0) mmdpart[b] = tt;
}

// ---------------------------------------------------------------------------
// Kernel 5: finalize — triplet loss + variance + MMD mean -> out[0]
// ---------------------------------------------------------------------------
__global__ __launch_bounds__(64) void finalize_kernel(
    const float* __restrict__ dist, const float* __restrict__ mmdpart,
    float* __restrict__ out) {
  int lane = threadIdx.x;
  float lv_po = 0.f;
  float dg[5];
#pragma unroll
  for (int g = 0; g < 5; ++g) dg[g] = 0.f;
  if (lane < 8) {
    const float* dr = dist + lane * 15;
    float dn[10];
#pragma unroll
    for (int g = 0; g < 5; ++g) dg[g] = dr[g];
#pragma unroll
    for (int k = 0; k < 10; ++k) dn[k] = dr[5 + k];
    float s1 = 0.f, s2 = 0.f;
    int nz = 0;
#pragma unroll
    for (int g = 0; g < 5; ++g) {
#pragma unroll
      for (int k = 0; k < 5; ++k) {
        float v2 = dg[g] + 1.0f - dn[k];
        if (v2 > 0.f) { s1 += v2; ++nz; }
      }
#pragma unroll
      for (int k = 5; k < 10; ++k) {
        float v2 = dg[g] + 1.0f - dn[k];
        if (v2 > 0.f) { s2 += v2; ++nz; }
      }
    }
    float only_pos = (dg[0] + dg[1] + dg[2] + dg[3] + dg[4]) * 0.002f;
    float lv = (s1 * 0.7f + s2 * 0.3f) / (float)(nz + 1);
    lv_po = lv + only_pos;
  }
  float tl = wred_sum(lv_po);
  tl = __shfl(tl, 0);

  // two-pass ddof=1 variance over the 40 dg values
  float psum = dg[0] + dg[1] + dg[2] + dg[3] + dg[4];
  float tsum = wred_sum(psum);
  float mean = __shfl(tsum, 0) * (1.f / 40.f);
  float pdev = 0.f;
  if (lane < 8) {
#pragma unroll
    for (int g = 0; g < 5; ++g) {
      float dd = dg[g] - mean;
      pdev = fmaf(dd, dd, pdev);
    }
  }
  float tdev = wred_sum(pdev);
  tdev = __shfl(tdev, 0);

  float msum = 0.f;
  for (int k2 = lane; k2 < 121; k2 += 64) msum += mmdpart[k2];
  float mt = wred_sum(msum);

  if (lane == 0) {
    float total_loss = tl * (1.f / 8.f);
    float var_g = (tdev / 39.f) * 0.1f;
    float mmd = mt * (1.f / 7744.f);
    out[0] = total_loss + mmd + var_g;
  }
}

__global__ __launch_bounds__(64) void zero_out_kernel(float* __restrict__ out,
                                                      int n) {
  int i = blockIdx.x * 64 + threadIdx.x;
  if (i < n) out[i] = 0.f;
}

// ---------------------------------------------------------------------------
extern "C" void kernel_launch(void* const* d_in, const int* in_sizes, int n_in,
                              void* d_out, int out_size, void* d_ws,
                              size_t ws_size, hipStream_t stream) {
  const float* data = (const float*)d_in[0];
  const int* lens = (const int*)d_in[1];
  float* out = (float*)d_out;
  char* ws = (char*)d_ws;

  const size_t HDR = 131072;  // dist/bwpart/mmdpart/l2buf region
  const size_t per_pair = (size_t)T_ * T_ * sizeof(float);  // 1 MB

  // Strict workspace guard: never touch bytes beyond ws_size.
  if (ws_size < HDR + per_pair) {
    zero_out_kernel<<<dim3((out_size + 63) / 64), 64, 0, stream>>>(out,
                                                                   out_size);
    return;
  }

  float* dist = (float*)(ws + 0);        // 120 floats
  float* bwpart = (float*)(ws + 1024);   // 253 floats
  float* mmdpart = (float*)(ws + 3072);  // 121 floats
  float* l2buf = (float*)(ws + 4096);    // 22*22*64 floats = 123904 B
  float* wbuf = (float*)(ws + HDR);

  size_t avail = ws_size - HDR;
  int PC = (int)(avail / per_pair);
  if (PC > NPAIR) PC = NPAIR;

  for (int p0 = 0; p0 < NPAIR; p0 += PC) {
    int pc = (NPAIR - p0) < PC ? (NPAIR - p0) : PC;
    gemm_kernel<<<dim3(64, pc), 256, 0, stream>>>(data, wbuf, p0);
    dtw_kernel<<<dim3(pc), 64, 0, stream>>>(wbuf, lens, dist, p0);
  }
  mmd_l2_kernel<<<dim3(253), 64, 0, stream>>>(data, l2buf, bwpart);
  mmd_k_kernel<<<dim3(121), 64, 0, stream>>>(l2buf, bwpart, mmdpart);
  finalize_kernel<<<dim3(1), 64, 0, stream>>>(dist, mmdpart, out);
}

// Round 9
// 271.654 us; speedup vs baseline: 1.7471x; 1.2074x over previous
//
#include <hip/hip_runtime.h>
#include <hip/hip_bf16.h>
#include <cstdint>
#include <cstddef>

#define T_ 512
#define DF 64
#define NPAIR 120
#define STEPW 16
#define NEGS (-(1 << 26))
#define RING 16  // LDS ring slots (rows in flight: 8 issued, 16-slot reuse gap)

// softmin constants: exp((m-x)/g) = exp2((m-x)*log2(e)/g); g*ln(2)
#define C1_ 0.28853900817779268f   // log2(e)/5
#define C2D 3.4657359027997265     // 5*ln(2), double

__device__ __forceinline__ float wred_sum(float v) {
#pragma unroll
  for (int o = 32; o > 0; o >>= 1) v += __shfl_down(v, o);
  return v;  // lane 0 holds the total
}

__device__ __forceinline__ int dexp(double x) {
  // biased-exponent field - 1023; 0.0 -> -1023 (safe "very small" marker)
  return (int)((__double_as_longlong(x) >> 52) & 0x7ff) - 1023;
}

// async global->LDS DMA, 16 B per lane: LDS dest = base + lane*16 (HW),
// global src = per-lane address (free row swizzle). Increments vmcnt.
__device__ __forceinline__ void dma16(const float* g, float* l) {
  __builtin_amdgcn_global_load_lds(
      (const __attribute__((address_space(1))) void*)g,
      (__attribute__((address_space(3))) void*)l, 16, 0, 0);
}

// ---------------------------------------------------------------------------
// Kernel 1: pairwise sq-dist GEMM; epilogue stores W = exp(-D/gamma) (fp32).
// ---------------------------------------------------------------------------
__global__ __launch_bounds__(256) void gemm_kernel(
    const float* __restrict__ data, float* __restrict__ wbuf, int pair0) {
  __shared__ float Xs[64][65];
  __shared__ float Ys[64][65];
  __shared__ float nrmx[64];
  __shared__ float nrmy[64];

  const int tile = blockIdx.x;   // 0..63 = (bi<<3)|bj
  const int pc = blockIdx.y;     // pair within chunk
  const int p = pair0 + pc;
  const int w = p / 15;
  const int o = p - w * 15;
  const int aidx = w * STEPW;
  const int oidx = aidx + 1 + o;
  const int i0 = (tile >> 3) << 6;
  const int j0 = (tile & 7) << 6;
  const int tid = threadIdx.x;

  const float* Xg = data + (size_t)aidx * (T_ * DF);
  const float* Yg = data + (size_t)oidx * (T_ * DF);

#pragma unroll
  for (int l = 0; l < 4; ++l) {
    int idx = tid + l * 256;  // 0..1023
    int r = idx >> 4;
    int c = idx & 15;
    float4 xv = reinterpret_cast<const float4*>(Xg + (size_t)(i0 + r) * DF)[c];
    float4 yv = reinterpret_cast<const float4*>(Yg + (size_t)(j0 + r) * DF)[c];
    Xs[r][4 * c + 0] = xv.x; Xs[r][4 * c + 1] = xv.y;
    Xs[r][4 * c + 2] = xv.z; Xs[r][4 * c + 3] = xv.w;
    Ys[r][4 * c + 0] = yv.x; Ys[r][4 * c + 1] = yv.y;
    Ys[r][4 * c + 2] = yv.z; Ys[r][4 * c + 3] = yv.w;
  }
  __syncthreads();

  if (tid < 128) {
    int r = tid & 63;
    const float* row = (tid < 64) ? Xs[r] : Ys[r];
    float s = 0.f;
#pragma unroll
    for (int k = 0; k < 64; ++k) s = fmaf(row[k], row[k], s);
    if (tid < 64) nrmx[r] = s; else nrmy[r] = s;
  }
  __syncthreads();

  const int tx = tid & 15;
  const int ty = tid >> 4;
  float acc[4][4];
#pragma unroll
  for (int a = 0; a < 4; ++a)
#pragma unroll
    for (int b = 0; b < 4; ++b) acc[a][b] = 0.f;

#pragma unroll 4
  for (int k = 0; k < 64; ++k) {
    float xr[4], yr[4];
#pragma unroll
    for (int a = 0; a < 4; ++a) xr[a] = Xs[ty * 4 + a][k];
#pragma unroll
    for (int b = 0; b < 4; ++b) yr[b] = Ys[tx * 4 + b][k];
#pragma unroll
    for (int a = 0; a < 4; ++a)
#pragma unroll
      for (int b = 0; b < 4; ++b) acc[a][b] = fmaf(xr[a], yr[b], acc[a][b]);
  }

  // epilogue: W = exp2(-d * log2e/gamma), coalesced float4 stores
  float* Wp = wbuf + (size_t)pc * (T_ * T_) + (size_t)i0 * T_ + j0;
#pragma unroll
  for (int a = 0; a < 4; ++a) {
    int ii = ty * 4 + a;
    float nx = nrmx[ii];
    float4 v;
    v.x = __builtin_exp2f(-(nx + nrmy[tx * 4 + 0] - 2.f * acc[a][0]) * C1_);
    v.y = __builtin_exp2f(-(nx + nrmy[tx * 4 + 1] - 2.f * acc[a][1]) * C1_);
    v.z = __builtin_exp2f(-(nx + nrmy[tx * 4 + 2] - 2.f * acc[a][2]) * C1_);
    v.w = __builtin_exp2f(-(nx + nrmy[tx * 4 + 3] - 2.f * acc[a][3]) * C1_);
    *reinterpret_cast<float4*>(Wp + (size_t)ii * T_ + tx * 4) = v;
  }
}

// ---------------------------------------------------------------------------
// Kernel 2: softDTW in EXP-DOMAIN, fp64 mantissa + per-lane block exponent.
// One wave per pair, zero barriers. Lane l owns cols [8l,8l+8), staggered
// 2 rows/lane.  E[i][j] = w[i][j]*(E_left + E_up + E_diag);  R = -g*ln(E).
// W staging: 16-slot LDS ring fed by global_load_lds DMAs with HAND-COUNTED
// s_waitcnt vmcnt(12) (14 DMAs always in flight, never drained). Register
// prefetch kept losing to the scheduler (r5: rotation drained per step;
// r7: VGPR_Count=68 proves the 8-slot pipeline was sunk to depth ~1).
// DMAs use no VGPRs -> nothing to sink. LDS->reg is double-buffered one
// step ahead (ds_read latency hides under the fp64 step).
// ---------------------------------------------------------------------------
__global__ __launch_bounds__(64) void dtw_kernel(
    const float* __restrict__ Wm, const int* __restrict__ lens,
    float* __restrict__ dist, int pair0) {
  __shared__ float slot[RING * T_];  // 16 slots x 2048 B = 32 KB

  const int pc = blockIdx.x;
  const int p = pair0 + pc;
  const int w = p / 15;
  const int o = p - w * 15;
  const int lx = lens[w * STEPW];
  const int ly = lens[w * STEPW + 1 + o];
  const int l = threadIdx.x;
  const int imax = lx - 1;
  const int jt = ly - 1;
  const int lt = jt >> 3, ct = jt & 7;
  const int nmax = imax + 2 * lt;
  const float invl = 1.f / (float)(lx + ly);

  const float* wp = Wm + (size_t)pc * (T_ * T_);

  // issue both 16B DMAs for virtual step vs: lane l stages row (vs-2l),
  // cols [8l, 8l+8) into slot vs%RING at float offsets 4l and 256+4l.
#define ISSUE(VS)                                                      \
  {                                                                    \
    const int vs_ = (VS);                                              \
    int r_ = vs_ - 2 * l;                                              \
    r_ = (r_ < 0) ? 0 : (r_ > T_ - 1 ? T_ - 1 : r_);                   \
    const float* gb_ = wp + (size_t)r_ * T_ + (l << 3);                \
    float* lb_ = &slot[(vs_ & (RING - 1)) * T_];                       \
    dma16(gb_, lb_);                                                   \
    dma16(gb_ + 4, lb_ + 256);                                         \
  }

  // prologue: steps 0..7 in flight (16 DMAs)
  ISSUE(0); ISSUE(1); ISSUE(2); ISSUE(3);
  ISSUE(4); ISSUE(5); ISSUE(6); ISSUE(7);

  // previous-row E (fp64 mantissas, one shared block exponent S)
  double e0 = 0., e1 = 0., e2 = 0., e3 = 0.;
  double e4 = 0., e5 = 0., e6 = 0., e7 = 0.;
  int S = NEGS;

  // boundary shuffle pipeline (value+scale pairs, 2-step slack)
  double pv = 0.;  int ps = NEGS;
  double bl1v = 0., bl2v = 0.;  int bl1S = NEGS, bl2S = NEGS;

  double out_v = 1.; int out_S = 0;

  // wait step 0 (leave steps 1..7 = 14 in flight), read it
  asm volatile("s_waitcnt vmcnt(14)" ::: "memory");
  __builtin_amdgcn_sched_barrier(0);
  float4 cur0 = *reinterpret_cast<const float4*>(&slot[4 * l]);
  float4 cur1 = *reinterpret_cast<const float4*>(&slot[256 + 4 * l]);

  for (int n = 0; n <= nmax; ++n) {
    // snapshot neighbor (e7, S) for consumption one step later
    double nv = __shfl_up(e7, 1);
    int ns = __shfl_up(S, 1);
    bl2v = bl1v; bl2S = bl1S;
    bl1v = pv;   bl1S = ps;
    const int i = n - 2 * l;
    if (l == 0) {
      bl1v = 0.; bl1S = NEGS;
      bl2v = (i == 0) ? 1. : 0.;
      bl2S = (i == 0) ? 0 : NEGS;
    }

    // step n+1's DMAs (issued at n-7) must be done; 12 = steps n+2..n+7
    asm volatile("s_waitcnt vmcnt(12)" ::: "memory");
    __builtin_amdgcn_sched_barrier(0);
    const int s1 = ((n + 1) & (RING - 1)) * T_;
    float4 nxt0 = *reinterpret_cast<const float4*>(&slot[s1 + 4 * l]);
    float4 nxt1 = *reinterpret_cast<const float4*>(&slot[s1 + 256 + 4 * l]);
    ISSUE(n + 8);  // refill: slot (n+8)%16, consumed 8 steps from now

    if ((unsigned)i <= (unsigned)imax) {
      double sum = ((e0 + e1) + (e2 + e3)) + ((e4 + e5) + (e6 + e7));
      int N = max(S + dexp(sum),
                  max(bl1S + dexp(bl1v), bl2S + dexp(bl2v)));
      const int dS = S - N;
      double u0 = ldexp(e0, dS), u1 = ldexp(e1, dS);
      double u2 = ldexp(e2, dS), u3 = ldexp(e3, dS);
      double u4 = ldexp(e4, dS), u5 = ldexp(e5, dS);
      double u6 = ldexp(e6, dS), u7 = ldexp(e7, dS);
      double L = ldexp(bl1v, bl1S - N);
      double G = ldexp(bl2v, bl2S - N);
      const double W0 = (double)cur0.x, W1 = (double)cur0.y;
      const double W2 = (double)cur0.z, W3 = (double)cur0.w;
      const double W4 = (double)cur1.x, W5 = (double)cur1.y;
      const double W6 = (double)cur1.z, W7 = (double)cur1.w;
      double q0 = W0 * ((L + G) + u0);
      double q1 = W1 * (u1 + u0);
      double q2 = W2 * (u2 + u1);
      double q3 = W3 * (u3 + u2);
      double q4 = W4 * (u4 + u3);
      double q5 = W5 * (u5 + u4);
      double q6 = W6 * (u6 + u5);
      double q7 = W7 * (u7 + u6);
      e0 = q0;
      e1 = fma(W1, e0, q1);
      e2 = fma(W2, e1, q2);
      e3 = fma(W3, e2, q3);
      e4 = fma(W4, e3, q4);
      e5 = fma(W5, e4, q5);
      e6 = fma(W6, e5, q6);
      e7 = fma(W7, e6, q7);
      S = N;
      if (n == nmax && l == lt) {
        out_v = (ct == 0) ? e0 : (ct == 1) ? e1 : (ct == 2) ? e2
              : (ct == 3) ? e3 : (ct == 4) ? e4 : (ct == 5) ? e5
              : (ct == 6) ? e6 : e7;
        out_S = N;
      }
    }
    pv = nv; ps = ns;
    cur0 = nxt0; cur1 = nxt1;
  }

  // drain: outstanding DMAs must not land in a successor block's LDS
  asm volatile("s_waitcnt vmcnt(0)" ::: "memory");

  if (l == lt) {
    // R = -gamma*ln(E) = -gamma*ln2*(log2(v) + S)
    double vv = (out_v > 0.) ? out_v : 1e-300;  // belt-and-braces
    double r = -C2D * (log2(vv) + (double)out_S);
    dist[p] = (float)(r * (double)invl);
  }
}

// ---------------------------------------------------------------------------
// Kernel 3: MMD pairwise per-feature L2 (upper triangle, mirrored)
// ---------------------------------------------------------------------------
__global__ __launch_bounds__(64) void mmd_l2_kernel(
    const float* __restrict__ data, float* __restrict__ l2buf,
    float* __restrict__ bwpart) {
  int b = blockIdx.x;  // 0..252 upper-tri (incl diag) index
  int u = 0, rem = b;
  while (rem >= 22 - u) { rem -= 22 - u; ++u; }
  int v = u + rem;
  int f = threadIdx.x;
  float s = 0.f;
  if (u != v) {
    int iu = u < 11 ? u : u + 5;
    int iv = v < 11 ? v : v + 5;
    const float* A = data + (size_t)iu * (T_ * DF) + f;
    const float* B = data + (size_t)iv * (T_ * DF) + f;
#pragma unroll 8
    for (int t = 0; t < T_; ++t) {
      float dd = A[(size_t)t * DF] - B[(size_t)t * DF];
      s = fmaf(dd, dd, s);
    }
  }
  l2buf[(size_t)(u * 22 + v) * 64 + f] = s;
  l2buf[(size_t)(v * 22 + u) * 64 + f] = s;
  float tot = wred_sum(s);
  if (f == 0) bwpart[b] = 2.f * tot;  // diag contributes exactly 0
}

// ---------------------------------------------------------------------------
// Kernel 4: MMD kernel sums per (a,c) of the 11x11 grid
// ---------------------------------------------------------------------------
__global__ __launch_bounds__(64) void mmd_k_kernel(
    const float* __restrict__ l2buf, const float* __restrict__ bwpart,
    float* __restrict__ mmdpart) {
  int b = blockIdx.x;  // 0..120
  int a = b / 11, c = b - a * 11;
  int f = threadIdx.x;
  float bs = 0.f;
  for (int k2 = f; k2 < 253; k2 += 64) bs += bwpart[k2];
  bs = wred_sum(bs);
  float bw = __shfl(bs, 0) * (1.f / (462.f * 4.f));  // /(n^2-n)/KMUL^(KNUM//2)
  float xx = l2buf[(size_t)(a * 22 + c) * 64 + f];
  float yy = l2buf[(size_t)((11 + a) * 22 + (11 + c)) * 64 + f];
  float xy = l2buf[(size_t)(a * 22 + (11 + c)) * 64 + f];
  float yx = l2buf[(size_t)((11 + a) * 22 + c) * 64 + f];
  float term = 0.f;
  float ib = 1.f / bw;
#pragma unroll
  for (int i = 0; i < 5; ++i) {
    term += expf(-xx * ib) + expf(-yy * ib) - expf(-xy * ib) - expf(-yx * ib);
    ib *= 0.5f;
  }
  float tt = wred_sum(term);
  if (f == 0) mmdpart[b] = tt;
}

// ---------------------------------------------------------------------------
// Kernel 5: finalize — triplet loss + variance + MMD mean -> out[0]
// ---------------------------------------------------------------------------
__global__ __launch_bounds__(64) void finalize_kernel(
    const float* __restrict__ dist, const float* __restrict__ mmdpart,
    float* __restrict__ out) {
  int lane = threadIdx.x;
  float lv_po = 0.f;
  float dg[5];
#pragma unroll
  for (int g = 0; g < 5; ++g) dg[g] = 0.f;
  if (lane < 8) {
    const float* dr = dist + lane * 15;
    float dn[10];
#pragma unroll
    for (int g = 0; g < 5; ++g) dg[g] = dr[g];
#pragma unroll
    for (int k = 0; k < 10; ++k) dn[k] = dr[5 + k];
    float s1 = 0.f, s2 = 0.f;
    int nz = 0;
#pragma unroll
    for (int g = 0; g < 5; ++g) {
#pragma unroll
      for (int k = 0; k < 5; ++k) {
        float v2 = dg[g] + 1.0f - dn[k];
        if (v2 > 0.f) { s1 += v2; ++nz; }
      }
#pragma unroll
      for (int k = 5; k < 10; ++k) {
        float v2 = dg[g] + 1.0f - dn[k];
        if (v2 > 0.f) { s2 += v2; ++nz; }
      }
    }
    float only_pos = (dg[0] + dg[1] + dg[2] + dg[3] + dg[4]) * 0.002f;
    float lv = (s1 * 0.7f + s2 * 0.3f) / (float)(nz + 1);
    lv_po = lv + only_pos;
  }
  float tl = wred_sum(lv_po);
  tl = __shfl(tl, 0);

  // two-pass ddof=1 variance over the 40 dg values
  float psum = dg[0] + dg[1] + dg[2] + dg[3] + dg[4];
  float tsum = wred_sum(psum);
  float mean = __shfl(tsum, 0) * (1.f / 40.f);
  float pdev = 0.f;
  if (lane < 8) {
#pragma unroll
    for (int g = 0; g < 5; ++g) {
      float dd = dg[g] - mean;
      pdev = fmaf(dd, dd, pdev);
    }
  }
  float tdev = wred_sum(pdev);
  tdev = __shfl(tdev, 0);

  float msum = 0.f;
  for (int k2 = lane; k2 < 121; k2 += 64) msum += mmdpart[k2];
  float mt = wred_sum(msum);

  if (lane == 0) {
    float total_loss = tl * (1.f / 8.f);
    float var_g = (tdev / 39.f) * 0.1f;
    float mmd = mt * (1.f / 7744.f);
    out[0] = total_loss + mmd + var_g;
  }
}

__global__ __launch_bounds__(64) void zero_out_kernel(float* __restrict__ out,
                                                      int n) {
  int i = blockIdx.x * 64 + threadIdx.x;
  if (i < n) out[i] = 0.f;
}

// ---------------------------------------------------------------------------
extern "C" void kernel_launch(void* const* d_in, const int* in_sizes, int n_in,
                              void* d_out, int out_size, void* d_ws,
                              size_t ws_size, hipStream_t stream) {
  const float* data = (const float*)d_in[0];
  const int* lens = (const int*)d_in[1];
  float* out = (float*)d_out;
  char* ws = (char*)d_ws;

  const size_t HDR = 131072;  // dist/bwpart/mmdpart/l2buf region
  const size_t per_pair = (size_t)T_ * T_ * sizeof(float);  // 1 MB

  // Strict workspace guard: never touch bytes beyond ws_size.
  if (ws_size < HDR + per_pair) {
    zero_out_kernel<<<dim3((out_size + 63) / 64), 64, 0, stream>>>(out,
                                                                   out_size);
    return;
  }

  float* dist = (float*)(ws + 0);        // 120 floats
  float* bwpart = (float*)(ws + 1024);   // 253 floats
  float* mmdpart = (float*)(ws + 3072);  // 121 floats
  float* l2buf = (float*)(ws + 4096);    // 22*22*64 floats = 123904 B
  float* wbuf = (float*)(ws + HDR);

  size_t avail = ws_size - HDR;
  int PC = (int)(avail / per_pair);
  if (PC > NPAIR) PC = NPAIR;

  for (int p0 = 0; p0 < NPAIR; p0 += PC) {
    int pc = (NPAIR - p0) < PC ? (NPAIR - p0) : PC;
    gemm_kernel<<<dim3(64, pc), 256, 0, stream>>>(data, wbuf, p0);
    dtw_kernel<<<dim3(pc), 64, 0, stream>>>(wbuf, lens, dist, p0);
  }
  mmd_l2_kernel<<<dim3(253), 64, 0, stream>>>(data, l2buf, bwpart);
  mmd_k_kernel<<<dim3(121), 64, 0, stream>>>(l2buf, bwpart, mmdpart);
  finalize_kernel<<<dim3(1), 64, 0, stream>>>(dist, mmdpart, out);
}

// Round 10
// 270.680 us; speedup vs baseline: 1.7534x; 1.0036x over previous
//
#include <hip/hip_runtime.h>
#include <hip/hip_bf16.h>
#include <cstdint>
#include <cstddef>

#define T_ 512
#define DF 64
#define NPAIR 120
#define STEPW 16
#define NEGS (-(1 << 26))
#define RING 16  // LDS ring slots

// softmin constants: exp((m-x)/g) = exp2((m-x)*log2(e)/g); g*ln(2)
#define C1_ 0.28853900817779268f   // log2(e)/5
#define C2D 3.4657359027997265     // 5*ln(2), double

__device__ __forceinline__ float wred_sum(float v) {
#pragma unroll
  for (int o = 32; o > 0; o >>= 1) v += __shfl_down(v, o);
  return v;  // lane 0 holds the total
}

__device__ __forceinline__ int dexp(double x) {
  // biased-exponent field - 1023; 0.0 -> -1023 (safe "very small" marker)
  return (int)((__double_as_longlong(x) >> 52) & 0x7ff) - 1023;
}

// async global->LDS DMA, 16 B per lane: LDS dest = base + lane*16 (HW),
// global src = per-lane address (free row swizzle). Increments vmcnt.
__device__ __forceinline__ void dma16(const float* g, float* l) {
  __builtin_amdgcn_global_load_lds(
      (const __attribute__((address_space(1))) void*)g,
      (__attribute__((address_space(3))) void*)l, 16, 0, 0);
}

// ---------------------------------------------------------------------------
// Kernel 1: pairwise sq-dist GEMM; epilogue stores W = exp(-D/gamma) (fp32).
// ---------------------------------------------------------------------------
__global__ __launch_bounds__(256) void gemm_kernel(
    const float* __restrict__ data, float* __restrict__ wbuf, int pair0) {
  __shared__ float Xs[64][65];
  __shared__ float Ys[64][65];
  __shared__ float nrmx[64];
  __shared__ float nrmy[64];

  const int tile = blockIdx.x;   // 0..63 = (bi<<3)|bj
  const int pc = blockIdx.y;     // pair within chunk
  const int p = pair0 + pc;
  const int w = p / 15;
  const int o = p - w * 15;
  const int aidx = w * STEPW;
  const int oidx = aidx + 1 + o;
  const int i0 = (tile >> 3) << 6;
  const int j0 = (tile & 7) << 6;
  const int tid = threadIdx.x;

  const float* Xg = data + (size_t)aidx * (T_ * DF);
  const float* Yg = data + (size_t)oidx * (T_ * DF);

#pragma unroll
  for (int l = 0; l < 4; ++l) {
    int idx = tid + l * 256;  // 0..1023
    int r = idx >> 4;
    int c = idx & 15;
    float4 xv = reinterpret_cast<const float4*>(Xg + (size_t)(i0 + r) * DF)[c];
    float4 yv = reinterpret_cast<const float4*>(Yg + (size_t)(j0 + r) * DF)[c];
    Xs[r][4 * c + 0] = xv.x; Xs[r][4 * c + 1] = xv.y;
    Xs[r][4 * c + 2] = xv.z; Xs[r][4 * c + 3] = xv.w;
    Ys[r][4 * c + 0] = yv.x; Ys[r][4 * c + 1] = yv.y;
    Ys[r][4 * c + 2] = yv.z; Ys[r][4 * c + 3] = yv.w;
  }
  __syncthreads();

  if (tid < 128) {
    int r = tid & 63;
    const float* row = (tid < 64) ? Xs[r] : Ys[r];
    float s = 0.f;
#pragma unroll
    for (int k = 0; k < 64; ++k) s = fmaf(row[k], row[k], s);
    if (tid < 64) nrmx[r] = s; else nrmy[r] = s;
  }
  __syncthreads();

  const int tx = tid & 15;
  const int ty = tid >> 4;
  float acc[4][4];
#pragma unroll
  for (int a = 0; a < 4; ++a)
#pragma unroll
    for (int b = 0; b < 4; ++b) acc[a][b] = 0.f;

#pragma unroll 4
  for (int k = 0; k < 64; ++k) {
    float xr[4], yr[4];
#pragma unroll
    for (int a = 0; a < 4; ++a) xr[a] = Xs[ty * 4 + a][k];
#pragma unroll
    for (int b = 0; b < 4; ++b) yr[b] = Ys[tx * 4 + b][k];
#pragma unroll
    for (int a = 0; a < 4; ++a)
#pragma unroll
      for (int b = 0; b < 4; ++b) acc[a][b] = fmaf(xr[a], yr[b], acc[a][b]);
  }

  // epilogue: W = exp2(-d * log2e/gamma), coalesced float4 stores
  float* Wp = wbuf + (size_t)pc * (T_ * T_) + (size_t)i0 * T_ + j0;
#pragma unroll
  for (int a = 0; a < 4; ++a) {
    int ii = ty * 4 + a;
    float nx = nrmx[ii];
    float4 v;
    v.x = __builtin_exp2f(-(nx + nrmy[tx * 4 + 0] - 2.f * acc[a][0]) * C1_);
    v.y = __builtin_exp2f(-(nx + nrmy[tx * 4 + 1] - 2.f * acc[a][1]) * C1_);
    v.z = __builtin_exp2f(-(nx + nrmy[tx * 4 + 2] - 2.f * acc[a][2]) * C1_);
    v.w = __builtin_exp2f(-(nx + nrmy[tx * 4 + 3] - 2.f * acc[a][3]) * C1_);
    *reinterpret_cast<float4*>(Wp + (size_t)ii * T_ + tx * 4) = v;
  }
}

// ---------------------------------------------------------------------------
// Kernel 2: softDTW in EXP-DOMAIN, fp64 mantissa + per-lane block exponent.
// One wave per pair, zero barriers. Lane l owns cols [8l,8l+8), staggered
// 2 rows/lane.  E[i][j] = w[i][j]*(E_left + E_up + E_diag);  R = -g*ln(E).
// W staging: 16-slot LDS ring fed by global_load_lds DMAs with hand-counted
// s_waitcnt vmcnt(12) (14 in flight, never drained) -- r9-verified.
// NEW (r10): full rescale (sum-tree exponent) only every 4th step; other
// steps keep the boundary-scale guard N=max(S,SL,SD) (r6 NaN lesson: the
// neighbor-scale max can NEVER be dropped) and skip alignment when dS==0.
// Drift safety: mantissa growth <=3x/step (<=27x over 3 steps, no overflow);
// worst decay 3*72+576 spread = 792 binades << fp64's 1074 window.
// ---------------------------------------------------------------------------
__global__ __launch_bounds__(64) void dtw_kernel(
    const float* __restrict__ Wm, const int* __restrict__ lens,
    float* __restrict__ dist, int pair0) {
  __shared__ float slot[RING * T_];  // 16 slots x 2048 B = 32 KB

  const int pc = blockIdx.x;
  const int p = pair0 + pc;
  const int w = p / 15;
  const int o = p - w * 15;
  const int lx = lens[w * STEPW];
  const int ly = lens[w * STEPW + 1 + o];
  const int l = threadIdx.x;
  const int imax = lx - 1;
  const int jt = ly - 1;
  const int lt = jt >> 3, ct = jt & 7;
  const int nmax = imax + 2 * lt;
  const float invl = 1.f / (float)(lx + ly);

  const float* wp = Wm + (size_t)pc * (T_ * T_);

  // issue both 16B DMAs for virtual step vs: lane l stages row (vs-2l),
  // cols [8l, 8l+8) into slot vs%RING at float offsets 4l and 256+4l.
#define ISSUE(VS)                                                      \
  {                                                                    \
    const int vs_ = (VS);                                              \
    int r_ = vs_ - 2 * l;                                              \
    r_ = (r_ < 0) ? 0 : (r_ > T_ - 1 ? T_ - 1 : r_);                   \
    const float* gb_ = wp + (size_t)r_ * T_ + (l << 3);                \
    float* lb_ = &slot[(vs_ & (RING - 1)) * T_];                       \
    dma16(gb_, lb_);                                                   \
    dma16(gb_ + 4, lb_ + 256);                                         \
  }

  // prologue: steps 0..7 in flight (16 DMAs)
  ISSUE(0); ISSUE(1); ISSUE(2); ISSUE(3);
  ISSUE(4); ISSUE(5); ISSUE(6); ISSUE(7);

  // previous-row E (fp64 mantissas, one shared block exponent S)
  double e0 = 0., e1 = 0., e2 = 0., e3 = 0.;
  double e4 = 0., e5 = 0., e6 = 0., e7 = 0.;
  int S = NEGS;

  // boundary shuffle pipeline (value+scale pairs, 2-step slack)
  double pv = 0.;  int ps = NEGS;
  double bl1v = 0., bl2v = 0.;  int bl1S = NEGS, bl2S = NEGS;

  // wait step 0 (leave steps 1..7 = 14 in flight), read it
  asm volatile("s_waitcnt vmcnt(14)" ::: "memory");
  __builtin_amdgcn_sched_barrier(0);
  float4 cur0 = *reinterpret_cast<const float4*>(&slot[4 * l]);
  float4 cur1 = *reinterpret_cast<const float4*>(&slot[256 + 4 * l]);

#define STEP(NN, RESC)                                                     \
  {                                                                        \
    const int n_ = (NN);                                                   \
    double nv = __shfl_up(e7, 1);                                          \
    int ns = __shfl_up(S, 1);                                              \
    bl2v = bl1v; bl2S = bl1S;                                              \
    bl1v = pv;   bl1S = ps;                                                \
    const int i = n_ - 2 * l;                                              \
    if (l == 0) {                                                          \
      bl1v = 0.; bl1S = NEGS;                                              \
      bl2v = (i == 0) ? 1. : 0.;                                           \
      bl2S = (i == 0) ? 0 : NEGS;                                          \
    }                                                                      \
    /* step n+1's DMAs (issued at n-7) must be done; 12 = n+2..n+7 */      \
    asm volatile("s_waitcnt vmcnt(12)" ::: "memory");                      \
    __builtin_amdgcn_sched_barrier(0);                                     \
    const int s1 = ((n_ + 1) & (RING - 1)) * T_;                           \
    float4 nxt0 = *reinterpret_cast<const float4*>(&slot[s1 + 4 * l]);     \
    float4 nxt1 = *reinterpret_cast<const float4*>(&slot[s1 + 256 + 4*l]); \
    ISSUE(n_ + 8);                                                         \
    if ((unsigned)i <= (unsigned)imax) {                                   \
      const int SL_ = bl1S + dexp(bl1v);                                   \
      const int SD_ = bl2S + dexp(bl2v);                                   \
      int N;                                                               \
      if (RESC) {                                                          \
        double sum = ((e0 + e1) + (e2 + e3)) + ((e4 + e5) + (e6 + e7));    \
        N = max(S + dexp(sum), max(SL_, SD_));                             \
      } else {                                                             \
        N = max(S, max(SL_, SD_));                                         \
      }                                                                    \
      const int dS = S - N;                                                \
      if (dS != 0) {                                                       \
        e0 = ldexp(e0, dS); e1 = ldexp(e1, dS);                            \
        e2 = ldexp(e2, dS); e3 = ldexp(e3, dS);                            \
        e4 = ldexp(e4, dS); e5 = ldexp(e5, dS);                            \
        e6 = ldexp(e6, dS); e7 = ldexp(e7, dS);                            \
      }                                                                    \
      double L = ldexp(bl1v, bl1S - N);                                    \
      double G = ldexp(bl2v, bl2S - N);                                    \
      const double W0 = (double)cur0.x, W1 = (double)cur0.y;               \
      const double W2 = (double)cur0.z, W3 = (double)cur0.w;               \
      const double W4 = (double)cur1.x, W5 = (double)cur1.y;               \
      const double W6 = (double)cur1.z, W7 = (double)cur1.w;               \
      double q0 = W0 * ((L + G) + e0);                                     \
      double q1 = W1 * (e1 + e0);                                          \
      double q2 = W2 * (e2 + e1);                                          \
      double q3 = W3 * (e3 + e2);                                          \
      double q4 = W4 * (e4 + e3);                                          \
      double q5 = W5 * (e5 + e4);                                          \
      double q6 = W6 * (e6 + e5);                                          \
      double q7 = W7 * (e7 + e6);                                          \
      e0 = q0;                                                             \
      e1 = fma(W1, e0, q1);                                                \
      e2 = fma(W2, e1, q2);                                                \
      e3 = fma(W3, e2, q3);                                                \
      e4 = fma(W4, e3, q4);                                                \
      e5 = fma(W5, e4, q5);                                                \
      e6 = fma(W6, e5, q6);                                                \
      e7 = fma(W7, e6, q7);                                                \
      S = N;                                                               \
    }                                                                      \
    pv = nv; ps = ns;                                                      \
    cur0 = nxt0; cur1 = nxt1;                                              \
  }

  // unroll by 4: full rescale on sub-step 0 only (compile-time specialized)
  const int nend = (nmax + 4) & ~3;  // multiple of 4, covers n = 0..nmax
  for (int nb = 0; nb < nend; nb += 4) {
    STEP(nb + 0, 1);
    STEP(nb + 1, 0);
    STEP(nb + 2, 0);
    STEP(nb + 3, 0);
  }

  // drain: outstanding DMAs must not land in a successor block's LDS
  asm volatile("s_waitcnt vmcnt(0)" ::: "memory");

  // lane lt last updated its registers at n == nmax (row imax) -- capture now
  if (l == lt) {
    double out_v = (ct == 0) ? e0 : (ct == 1) ? e1 : (ct == 2) ? e2
                 : (ct == 3) ? e3 : (ct == 4) ? e4 : (ct == 5) ? e5
                 : (ct == 6) ? e6 : e7;
    double vv = (out_v > 0.) ? out_v : 1e-300;  // belt-and-braces
    double r = -C2D * (log2(vv) + (double)S);
    dist[p] = (float)(r * (double)invl);
  }
}

// ---------------------------------------------------------------------------
// Kernel 3: MMD pairwise per-feature L2 (upper triangle, mirrored)
// ---------------------------------------------------------------------------
__global__ __launch_bounds__(64) void mmd_l2_kernel(
    const float* __restrict__ data, float* __restrict__ l2buf,
    float* __restrict__ bwpart) {
  int b = blockIdx.x;  // 0..252 upper-tri (incl diag) index
  int u = 0, rem = b;
  while (rem >= 22 - u) { rem -= 22 - u; ++u; }
  int v = u + rem;
  int f = threadIdx.x;
  float s = 0.f;
  if (u != v) {
    int iu = u < 11 ? u : u + 5;
    int iv = v < 11 ? v : v + 5;
    const float* A = data + (size_t)iu * (T_ * DF) + f;
    const float* B = data + (size_t)iv * (T_ * DF) + f;
#pragma unroll 8
    for (int t = 0; t < T_; ++t) {
      float dd = A[(size_t)t * DF] - B[(size_t)t * DF];
      s = fmaf(dd, dd, s);
    }
  }
  l2buf[(size_t)(u * 22 + v) * 64 + f] = s;
  l2buf[(size_t)(v * 22 + u) * 64 + f] = s;
  float tot = wred_sum(s);
  if (f == 0) bwpart[b] = 2.f * tot;  // diag contributes exactly 0
}

// ---------------------------------------------------------------------------
// Kernel 4: MMD kernel sums per (a,c) of the 11x11 grid
// ---------------------------------------------------------------------------
__global__ __launch_bounds__(64) void mmd_k_kernel(
    const float* __restrict__ l2buf, const float* __restrict__ bwpart,
    float* __restrict__ mmdpart) {
  int b = blockIdx.x;  // 0..120
  int a = b / 11, c = b - a * 11;
  int f = threadIdx.x;
  float bs = 0.f;
  for (int k2 = f; k2 < 253; k2 += 64) bs += bwpart[k2];
  bs = wred_sum(bs);
  float bw = __shfl(bs, 0) * (1.f / (462.f * 4.f));  // /(n^2-n)/KMUL^(KNUM//2)
  float xx = l2buf[(size_t)(a * 22 + c) * 64 + f];
  float yy = l2buf[(size_t)((11 + a) * 22 + (11 + c)) * 64 + f];
  float xy = l2buf[(size_t)(a * 22 + (11 + c)) * 64 + f];
  float yx = l2buf[(size_t)((11 + a) * 22 + c) * 64 + f];
  float term = 0.f;
  float ib = 1.f / bw;
#pragma unroll
  for (int i = 0; i < 5; ++i) {
    term += expf(-xx * ib) + expf(-yy * ib) - expf(-xy * ib) - expf(-yx * ib);
    ib *= 0.5f;
  }
  float tt = wred_sum(term);
  if (f == 0) mmdpart[b] = tt;
}

// ---------------------------------------------------------------------------
// Kernel 5: finalize — triplet loss + variance + MMD mean -> out[0]
// ---------------------------------------------------------------------------
__global__ __launch_bounds__(64) void finalize_kernel(
    const float* __restrict__ dist, const float* __restrict__ mmdpart,
    float* __restrict__ out) {
  int lane = threadIdx.x;
  float lv_po = 0.f;
  float dg[5];
#pragma unroll
  for (int g = 0; g < 5; ++g) dg[g] = 0.f;
  if (lane < 8) {
    const float* dr = dist + lane * 15;
    float dn[10];
#pragma unroll
    for (int g = 0; g < 5; ++g) dg[g] = dr[g];
#pragma unroll
    for (int k = 0; k < 10; ++k) dn[k] = dr[5 + k];
    float s1 = 0.f, s2 = 0.f;
    int nz = 0;
#pragma unroll
    for (int g = 0; g < 5; ++g) {
#pragma unroll
      for (int k = 0; k < 5; ++k) {
        float v2 = dg[g] + 1.0f - dn[k];
        if (v2 > 0.f) { s1 += v2; ++nz; }
      }
#pragma unroll
      for (int k = 5; k < 10; ++k) {
        float v2 = dg[g] + 1.0f - dn[k];
        if (v2 > 0.f) { s2 += v2; ++nz; }
      }
    }
    float only_pos = (dg[0] + dg[1] + dg[2] + dg[3] + dg[4]) * 0.002f;
    float lv = (s1 * 0.7f + s2 * 0.3f) / (float)(nz + 1);
    lv_po = lv + only_pos;
  }
  float tl = wred_sum(lv_po);
  tl = __shfl(tl, 0);

  // two-pass ddof=1 variance over the 40 dg values
  float psum = dg[0] + dg[1] + dg[2] + dg[3] + dg[4];
  float tsum = wred_sum(psum);
  float mean = __shfl(tsum, 0) * (1.f / 40.f);
  float pdev = 0.f;
  if (lane < 8) {
#pragma unroll
    for (int g = 0; g < 5; ++g) {
      float dd = dg[g] - mean;
      pdev = fmaf(dd, dd, pdev);
    }
  }
  float tdev = wred_sum(pdev);
  tdev = __shfl(tdev, 0);

  float msum = 0.f;
  for (int k2 = lane; k2 < 121; k2 += 64) msum += mmdpart[k2];
  float mt = wred_sum(msum);

  if (lane == 0) {
    float total_loss = tl * (1.f / 8.f);
    float var_g = (tdev / 39.f) * 0.1f;
    float mmd = mt * (1.f / 7744.f);
    out[0] = total_loss + mmd + var_g;
  }
}

__global__ __launch_bounds__(64) void zero_out_kernel(float* __restrict__ out,
                                                      int n) {
  int i = blockIdx.x * 64 + threadIdx.x;
  if (i < n) out[i] = 0.f;
}

// ---------------------------------------------------------------------------
extern "C" void kernel_launch(void* const* d_in, const int* in_sizes, int n_in,
                              void* d_out, int out_size, void* d_ws,
                              size_t ws_size, hipStream_t stream) {
  const float* data = (const float*)d_in[0];
  const int* lens = (const int*)d_in[1];
  float* out = (float*)d_out;
  char* ws = (char*)d_ws;

  const size_t HDR = 131072;  // dist/bwpart/mmdpart/l2buf region
  const size_t per_pair = (size_t)T_ * T_ * sizeof(float);  // 1 MB

  // Strict workspace guard: never touch bytes beyond ws_size.
  if (ws_size < HDR + per_pair) {
    zero_out_kernel<<<dim3((out_size + 63) / 64), 64, 0, stream>>>(out,
                                                                   out_size);
    return;
  }

  float* dist = (float*)(ws + 0);        // 120 floats
  float* bwpart = (float*)(ws + 1024);   // 253 floats
  float* mmdpart = (float*)(ws + 3072);  // 121 floats
  float* l2buf = (float*)(ws + 4096);    // 22*22*64 floats = 123904 B
  float* wbuf = (float*)(ws + HDR);

  size_t avail = ws_size - HDR;
  int PC = (int)(avail / per_pair);
  if (PC > NPAIR) PC = NPAIR;

  for (int p0 = 0; p0 < NPAIR; p0 += PC) {
    int pc = (NPAIR - p0) < PC ? (NPAIR - p0) : PC;
    gemm_kernel<<<dim3(64, pc), 256, 0, stream>>>(data, wbuf, p0);
    dtw_kernel<<<dim3(pc), 64, 0, stream>>>(wbuf, lens, dist, p0);
  }
  mmd_l2_kernel<<<dim3(253), 64, 0, stream>>>(data, l2buf, bwpart);
  mmd_k_kernel<<<dim3(121), 64, 0, stream>>>(l2buf, bwpart, mmdpart);
  finalize_kernel<<<dim3(1), 64, 0, stream>>>(dist, mmdpart, out);
}

// Round 12
// 266.255 us; speedup vs baseline: 1.7825x; 1.0166x over previous
//
#include <hip/hip_runtime.h>
#include <hip/hip_bf16.h>
#include <cstdint>
#include <cstddef>

#define T_ 512
#define DF 64
#define NPAIR 120
#define STEPW 16
#define NEGS (-(1 << 26))
#define RING 16   // LDS ring slots
#define NSK 640   // skewed-W rows per pair (638 used, padded)

// softmin constants: exp((m-x)/g) = exp2((m-x)*log2(e)/g); g*ln(2)
#define C1_ 0.28853900817779268f   // log2(e)/5
#define C2D 3.4657359027997265     // 5*ln(2), double

__device__ __forceinline__ float wred_sum(float v) {
#pragma unroll
  for (int o = 32; o > 0; o >>= 1) v += __shfl_down(v, o);
  return v;  // lane 0 holds the total
}

__device__ __forceinline__ int dexp(double x) {
  // biased-exponent field - 1023; 0.0 -> -1023 (safe "very small" marker)
  return (int)((__double_as_longlong(x) >> 52) & 0x7ff) - 1023;
}

// async global->LDS DMA, 16 B per lane: LDS dest = base + lane*16 (HW),
// global src = per-lane address. Increments vmcnt.
__device__ __forceinline__ void dma16(const float* g, float* l) {
  __builtin_amdgcn_global_load_lds(
      (const __attribute__((address_space(1))) void*)g,
      (__attribute__((address_space(3))) void*)l, 16, 0, 0);
}

// ---------------------------------------------------------------------------
// Kernel 1: pairwise sq-dist GEMM; epilogue stores W = exp(-D/gamma) in
// STAGGER-SKEWED layout: WS[i + 2*(j>>3)][j] = W[i][j].  This makes the DTW
// kernel's per-step working set one contiguous 2 KB row (coalesced DMA);
// r10 post-mortem showed the scattered 64-line gathers were the step clock.
// r12 fix: skew row is (i0 + ii) + 2*g8 -- r11 dropped i0 (never ran: infra).
// ---------------------------------------------------------------------------
__global__ __launch_bounds__(256) void gemm_kernel(
    const float* __restrict__ data, float* __restrict__ wbuf, int pair0) {
  __shared__ float Xs[64][65];
  __shared__ float Ys[64][65];
  __shared__ float nrmx[64];
  __shared__ float nrmy[64];

  const int tile = blockIdx.x;   // 0..63 = (bi<<3)|bj
  const int pc = blockIdx.y;     // pair within chunk
  const int p = pair0 + pc;
  const int w = p / 15;
  const int o = p - w * 15;
  const int aidx = w * STEPW;
  const int oidx = aidx + 1 + o;
  const int i0 = (tile >> 3) << 6;
  const int j0 = (tile & 7) << 6;
  const int tid = threadIdx.x;

  const float* Xg = data + (size_t)aidx * (T_ * DF);
  const float* Yg = data + (size_t)oidx * (T_ * DF);

#pragma unroll
  for (int l = 0; l < 4; ++l) {
    int idx = tid + l * 256;  // 0..1023
    int r = idx >> 4;
    int c = idx & 15;
    float4 xv = reinterpret_cast<const float4*>(Xg + (size_t)(i0 + r) * DF)[c];
    float4 yv = reinterpret_cast<const float4*>(Yg + (size_t)(j0 + r) * DF)[c];
    Xs[r][4 * c + 0] = xv.x; Xs[r][4 * c + 1] = xv.y;
    Xs[r][4 * c + 2] = xv.z; Xs[r][4 * c + 3] = xv.w;
    Ys[r][4 * c + 0] = yv.x; Ys[r][4 * c + 1] = yv.y;
    Ys[r][4 * c + 2] = yv.z; Ys[r][4 * c + 3] = yv.w;
  }
  __syncthreads();

  if (tid < 128) {
    int r = tid & 63;
    const float* row = (tid < 64) ? Xs[r] : Ys[r];
    float s = 0.f;
#pragma unroll
    for (int k = 0; k < 64; ++k) s = fmaf(row[k], row[k], s);
    if (tid < 64) nrmx[r] = s; else nrmy[r] = s;
  }
  __syncthreads();

  const int tx = tid & 15;
  const int ty = tid >> 4;
  float acc[4][4];
#pragma unroll
  for (int a = 0; a < 4; ++a)
#pragma unroll
    for (int b = 0; b < 4; ++b) acc[a][b] = 0.f;

#pragma unroll 4
  for (int k = 0; k < 64; ++k) {
    float xr[4], yr[4];
#pragma unroll
    for (int a = 0; a < 4; ++a) xr[a] = Xs[ty * 4 + a][k];
#pragma unroll
    for (int b = 0; b < 4; ++b) yr[b] = Ys[tx * 4 + b][k];
#pragma unroll
    for (int a = 0; a < 4; ++a)
#pragma unroll
      for (int b = 0; b < 4; ++b) acc[a][b] = fmaf(xr[a], yr[b], acc[a][b]);
  }

  // epilogue: W = exp2(-d*log2e/gamma), stored skewed. The float4 at
  // (i0+ii, j0+tx*4) lies in ONE 8-col group (g8 const per thread) ->
  // still a single float4 store, at skew row n = i0 + ii + 2*g8.
  const int g8 = (j0 >> 3) + (tx >> 1);
  float* Wp = wbuf + (size_t)pc * (NSK * T_) + j0 + tx * 4;
#pragma unroll
  for (int a = 0; a < 4; ++a) {
    int ii = ty * 4 + a;
    float nx = nrmx[ii];
    float4 v;
    v.x = __builtin_exp2f(-(nx + nrmy[tx * 4 + 0] - 2.f * acc[a][0]) * C1_);
    v.y = __builtin_exp2f(-(nx + nrmy[tx * 4 + 1] - 2.f * acc[a][1]) * C1_);
    v.z = __builtin_exp2f(-(nx + nrmy[tx * 4 + 2] - 2.f * acc[a][2]) * C1_);
    v.w = __builtin_exp2f(-(nx + nrmy[tx * 4 + 3] - 2.f * acc[a][3]) * C1_);
    *reinterpret_cast<float4*>(Wp + (size_t)(i0 + ii + 2 * g8) * T_) = v;
  }
}

// ---------------------------------------------------------------------------
// Kernel 2: softDTW in EXP-DOMAIN, fp64 mantissa + per-lane block exponent.
// One wave per pair, zero barriers. Lane l owns cols [8l,8l+8), staggered
// 2 rows/lane.  E[i][j] = w[i][j]*(E_left + E_up + E_diag);  R = -g*ln(E).
// W staging: 16-slot LDS ring fed by COALESCED global_load_lds DMAs (the
// skewed layout puts step n's whole working set in row n of WS) with
// hand-counted s_waitcnt vmcnt(12) (14 in flight, never drained).
// ---------------------------------------------------------------------------
__global__ __launch_bounds__(64) void dtw_kernel(
    const float* __restrict__ Wm, const int* __restrict__ lens,
    float* __restrict__ dist, int pair0) {
  __shared__ float slot[RING * T_];  // 16 slots x 2048 B = 32 KB

  const int pc = blockIdx.x;
  const int p = pair0 + pc;
  const int w = p / 15;
  const int o = p - w * 15;
  const int lx = lens[w * STEPW];
  const int ly = lens[w * STEPW + 1 + o];
  const int l = threadIdx.x;
  const int imax = lx - 1;
  const int jt = ly - 1;
  const int lt = jt >> 3, ct = jt & 7;
  const int nmax = imax + 2 * lt;
  const float invl = 1.f / (float)(lx + ly);

  const float* wp = Wm + (size_t)pc * (NSK * T_);

  // step vs's data = WS row vs (contiguous 2 KB). DMA0 copies row bytes
  // [0,1024) (lane*16), DMA1 copies [1024,2048); slot = linear row copy.
#define ISSUE(VS)                                                      \
  {                                                                    \
    int r_ = (VS);                                                     \
    r_ = (r_ > 637) ? 637 : r_;                                        \
    const float* gb_ = wp + (size_t)r_ * T_ + (l << 2);                \
    float* lb_ = &slot[((VS) & (RING - 1)) * T_];                      \
    dma16(gb_, lb_);                                                   \
    dma16(gb_ + 256, lb_ + 256);                                       \
  }

  // prologue: steps 0..7 in flight (16 DMAs)
  ISSUE(0); ISSUE(1); ISSUE(2); ISSUE(3);
  ISSUE(4); ISSUE(5); ISSUE(6); ISSUE(7);

  // previous-row E (fp64 mantissas, one shared block exponent S)
  double e0 = 0., e1 = 0., e2 = 0., e3 = 0.;
  double e4 = 0., e5 = 0., e6 = 0., e7 = 0.;
  int S = NEGS;

  // boundary shuffle pipeline (value+scale pairs, 2-step slack)
  double pv = 0.;  int ps = NEGS;
  double bl1v = 0., bl2v = 0.;  int bl1S = NEGS, bl2S = NEGS;

  // wait step 0 (leave steps 1..7 = 14 in flight), read it
  asm volatile("s_waitcnt vmcnt(14)" ::: "memory");
  __builtin_amdgcn_sched_barrier(0);
  float4 cur0 = *reinterpret_cast<const float4*>(&slot[8 * l]);
  float4 cur1 = *reinterpret_cast<const float4*>(&slot[8 * l + 4]);

#define STEP(NN, RESC)                                                     \
  {                                                                        \
    const int n_ = (NN);                                                   \
    double nv = __shfl_up(e7, 1);                                          \
    int ns = __shfl_up(S, 1);                                              \
    bl2v = bl1v; bl2S = bl1S;                                              \
    bl1v = pv;   bl1S = ps;                                                \
    const int i = n_ - 2 * l;                                              \
    if (l == 0) {                                                          \
      bl1v = 0.; bl1S = NEGS;                                              \
      bl2v = (i == 0) ? 1. : 0.;                                           \
      bl2S = (i == 0) ? 0 : NEGS;                                          \
    }                                                                      \
    /* step n+1's DMAs (issued at n-7) must be done; 12 = n+2..n+7 */      \
    asm volatile("s_waitcnt vmcnt(12)" ::: "memory");                      \
    __builtin_amdgcn_sched_barrier(0);                                     \
    const int s1 = ((n_ + 1) & (RING - 1)) * T_;                           \
    float4 nxt0 = *reinterpret_cast<const float4*>(&slot[s1 + 8 * l]);     \
    float4 nxt1 = *reinterpret_cast<const float4*>(&slot[s1 + 8 * l + 4]); \
    ISSUE(n_ + 8);                                                         \
    if ((unsigned)i <= (unsigned)imax) {                                   \
      const int SL_ = bl1S + dexp(bl1v);                                   \
      const int SD_ = bl2S + dexp(bl2v);                                   \
      int N;                                                               \
      if (RESC) {                                                          \
        double sum = ((e0 + e1) + (e2 + e3)) + ((e4 + e5) + (e6 + e7));    \
        N = max(S + dexp(sum), max(SL_, SD_));                             \
      } else {                                                             \
        N = max(S, max(SL_, SD_));                                         \
      }                                                                    \
      const int dS = S - N;                                                \
      if (dS != 0) {                                                       \
        e0 = ldexp(e0, dS); e1 = ldexp(e1, dS);                            \
        e2 = ldexp(e2, dS); e3 = ldexp(e3, dS);                            \
        e4 = ldexp(e4, dS); e5 = ldexp(e5, dS);                            \
        e6 = ldexp(e6, dS); e7 = ldexp(e7, dS);                            \
      }                                                                    \
      double L = ldexp(bl1v, bl1S - N);                                    \
      double G = ldexp(bl2v, bl2S - N);                                    \
      const double W0 = (double)cur0.x, W1 = (double)cur0.y;               \
      const double W2 = (double)cur0.z, W3 = (double)cur0.w;               \
      const double W4 = (double)cur1.x, W5 = (double)cur1.y;               \
      const double W6 = (double)cur1.z, W7 = (double)cur1.w;               \
      double q0 = W0 * ((L + G) + e0);                                     \
      double q1 = W1 * (e1 + e0);                                          \
      double q2 = W2 * (e2 + e1);                                          \
      double q3 = W3 * (e3 + e2);                                          \
      double q4 = W4 * (e4 + e3);                                          \
      double q5 = W5 * (e5 + e4);                                          \
      double q6 = W6 * (e6 + e5);                                          \
      double q7 = W7 * (e7 + e6);                                          \
      e0 = q0;                                                             \
      e1 = fma(W1, e0, q1);                                                \
      e2 = fma(W2, e1, q2);                                                \
      e3 = fma(W3, e2, q3);                                                \
      e4 = fma(W4, e3, q4);                                                \
      e5 = fma(W5, e4, q5);                                                \
      e6 = fma(W6, e5, q6);                                                \
      e7 = fma(W7, e6, q7);                                                \
      S = N;                                                               \
    }                                                                      \
    pv = nv; ps = ns;                                                      \
    cur0 = nxt0; cur1 = nxt1;                                              \
  }

  // unroll by 4: full rescale on sub-step 0 only (compile-time specialized)
  const int nend = (nmax + 4) & ~3;  // multiple of 4, covers n = 0..nmax
  for (int nb = 0; nb < nend; nb += 4) {
    STEP(nb + 0, 1);
    STEP(nb + 1, 0);
    STEP(nb + 2, 0);
    STEP(nb + 3, 0);
  }

  // drain: outstanding DMAs must not land in a successor block's LDS
  asm volatile("s_waitcnt vmcnt(0)" ::: "memory");

  // lane lt last updated its registers at n == nmax (row imax) -- capture now
  if (l == lt) {
    double out_v = (ct == 0) ? e0 : (ct == 1) ? e1 : (ct == 2) ? e2
                 : (ct == 3) ? e3 : (ct == 4) ? e4 : (ct == 5) ? e5
                 : (ct == 6) ? e6 : e7;
    double vv = (out_v > 0.) ? out_v : 1e-300;  // belt-and-braces
    double r = -C2D * (log2(vv) + (double)S);
    dist[p] = (float)(r * (double)invl);
  }
}

// ---------------------------------------------------------------------------
// Kernel 3: MMD pairwise per-feature L2 (upper triangle, mirrored)
// ---------------------------------------------------------------------------
__global__ __launch_bounds__(64) void mmd_l2_kernel(
    const float* __restrict__ data, float* __restrict__ l2buf,
    float* __restrict__ bwpart) {
  int b = blockIdx.x;  // 0..252 upper-tri (incl diag) index
  int u = 0, rem = b;
  while (rem >= 22 - u) { rem -= 22 - u; ++u; }
  int v = u + rem;
  int f = threadIdx.x;
  float s = 0.f;
  if (u != v) {
    int iu = u < 11 ? u : u + 5;
    int iv = v < 11 ? v : v + 5;
    const float* A = data + (size_t)iu * (T_ * DF) + f;
    const float* B = data + (size_t)iv * (T_ * DF) + f;
#pragma unroll 8
    for (int t = 0; t < T_; ++t) {
      float dd = A[(size_t)t * DF] - B[(size_t)t * DF];
      s = fmaf(dd, dd, s);
    }
  }
  l2buf[(size_t)(u * 22 + v) * 64 + f] = s;
  l2buf[(size_t)(v * 22 + u) * 64 + f] = s;
  float tot = wred_sum(s);
  if (f == 0) bwpart[b] = 2.f * tot;  // diag contributes exactly 0
}

// ---------------------------------------------------------------------------
// Kernel 4: MMD kernel sums per (a,c) of the 11x11 grid
// ---------------------------------------------------------------------------
__global__ __launch_bounds__(64) void mmd_k_kernel(
    const float* __restrict__ l2buf, const float* __restrict__ bwpart,
    float* __restrict__ mmdpart) {
  int b = blockIdx.x;  // 0..120
  int a = b / 11, c = b - a * 11;
  int f = threadIdx.x;
  float bs = 0.f;
  for (int k2 = f; k2 < 253; k2 += 64) bs += bwpart[k2];
  bs = wred_sum(bs);
  float bw = __shfl(bs, 0) * (1.f / (462.f * 4.f));  // /(n^2-n)/KMUL^(KNUM//2)
  float xx = l2buf[(size_t)(a * 22 + c) * 64 + f];
  float yy = l2buf[(size_t)((11 + a) * 22 + (11 + c)) * 64 + f];
  float xy = l2buf[(size_t)(a * 22 + (11 + c)) * 64 + f];
  float yx = l2buf[(size_t)((11 + a) * 22 + c) * 64 + f];
  float term = 0.f;
  float ib = 1.f / bw;
#pragma unroll
  for (int i = 0; i < 5; ++i) {
    term += expf(-xx * ib) + expf(-yy * ib) - expf(-xy * ib) - expf(-yx * ib);
    ib *= 0.5f;
  }
  float tt = wred_sum(term);
  if (f == 0) mmdpart[b] = tt;
}

// ---------------------------------------------------------------------------
// Kernel 5: finalize — triplet loss + variance + MMD mean -> out[0]
// ---------------------------------------------------------------------------
__global__ __launch_bounds__(64) void finalize_kernel(
    const float* __restrict__ dist, const float* __restrict__ mmdpart,
    float* __restrict__ out) {
  int lane = threadIdx.x;
  float lv_po = 0.f;
  float dg[5];
#pragma unroll
  for (int g = 0; g < 5; ++g) dg[g] = 0.f;
  if (lane < 8) {
    const float* dr = dist + lane * 15;
    float dn[10];
#pragma unroll
    for (int g = 0; g < 5; ++g) dg[g] = dr[g];
#pragma unroll
    for (int k = 0; k < 10; ++k) dn[k] = dr[5 + k];
    float s1 = 0.f, s2 = 0.f;
    int nz = 0;
#pragma unroll
    for (int g = 0; g < 5; ++g) {
#pragma unroll
      for (int k = 0; k < 5; ++k) {
        float v2 = dg[g] + 1.0f - dn[k];
        if (v2 > 0.f) { s1 += v2; ++nz; }
      }
#pragma unroll
      for (int k = 5; k < 10; ++k) {
        float v2 = dg[g] + 1.0f - dn[k];
        if (v2 > 0.f) { s2 += v2; ++nz; }
      }
    }
    float only_pos = (dg[0] + dg[1] + dg[2] + dg[3] + dg[4]) * 0.002f;
    float lv = (s1 * 0.7f + s2 * 0.3f) / (float)(nz + 1);
    lv_po = lv + only_pos;
  }
  float tl = wred_sum(lv_po);
  tl = __shfl(tl, 0);

  // two-pass ddof=1 variance over the 40 dg values
  float psum = dg[0] + dg[1] + dg[2] + dg[3] + dg[4];
  float tsum = wred_sum(psum);
  float mean = __shfl(tsum, 0) * (1.f / 40.f);
  float pdev = 0.f;
  if (lane < 8) {
#pragma unroll
    for (int g = 0; g < 5; ++g) {
      float dd = dg[g] - mean;
      pdev = fmaf(dd, dd, pdev);
    }
  }
  float tdev = wred_sum(pdev);
  tdev = __shfl(tdev, 0);

  float msum = 0.f;
  for (int k2 = lane; k2 < 121; k2 += 64) msum += mmdpart[k2];
  float mt = wred_sum(msum);

  if (lane == 0) {
    float total_loss = tl * (1.f / 8.f);
    float var_g = (tdev / 39.f) * 0.1f;
    float mmd = mt * (1.f / 7744.f);
    out[0] = total_loss + mmd + var_g;
  }
}

__global__ __launch_bounds__(64) void zero_out_kernel(float* __restrict__ out,
                                                      int n) {
  int i = blockIdx.x * 64 + threadIdx.x;
  if (i < n) out[i] = 0.f;
}

// ---------------------------------------------------------------------------
extern "C" void kernel_launch(void* const* d_in, const int* in_sizes, int n_in,
                              void* d_out, int out_size, void* d_ws,
                              size_t ws_size, hipStream_t stream) {
  const float* data = (const float*)d_in[0];
  const int* lens = (const int*)d_in[1];
  float* out = (float*)d_out;
  char* ws = (char*)d_ws;

  const size_t HDR = 131072;  // dist/bwpart/mmdpart/l2buf region
  const size_t per_pair = (size_t)NSK * T_ * sizeof(float);  // 1.31 MB

  // Strict workspace guard: never touch bytes beyond ws_size.
  if (ws_size < HDR + per_pair) {
    zero_out_kernel<<<dim3((out_size + 63) / 64), 64, 0, stream>>>(out,
                                                                   out_size);
    return;
  }

  float* dist = (float*)(ws + 0);        // 120 floats
  float* bwpart = (float*)(ws + 1024);   // 253 floats
  float* mmdpart = (float*)(ws + 3072);  // 121 floats
  float* l2buf = (float*)(ws + 4096);    // 22*22*64 floats = 123904 B
  float* wbuf = (float*)(ws + HDR);

  size_t avail = ws_size - HDR;
  int PC = (int)(avail / per_pair);
  if (PC > NPAIR) PC = NPAIR;

  for (int p0 = 0; p0 < NPAIR; p0 += PC) {
    int pc = (NPAIR - p0) < PC ? (NPAIR - p0) : PC;
    gemm_kernel<<<dim3(64, pc), 256, 0, stream>>>(data, wbuf, p0);
    dtw_kernel<<<dim3(pc), 64, 0, stream>>>(wbuf, lens, dist, p0);
  }
  mmd_l2_kernel<<<dim3(253), 64, 0, stream>>>(data, l2buf, bwpart);
  mmd_k_kernel<<<dim3(121), 64, 0, stream>>>(l2buf, bwpart, mmdpart);
  finalize_kernel<<<dim3(1), 64, 0, stream>>>(dist, mmdpart, out);
}

// Round 13
// 249.937 us; speedup vs baseline: 1.8989x; 1.0653x over previous
//
#include <hip/hip_runtime.h>
#include <hip/hip_bf16.h>
#include <cstdint>
#include <cstddef>

#define T_ 512
#define DF 64
#define NPAIR 120
#define STEPW 16
#define NEGS (-(1 << 26))
#define RING 32   // LDS ring slots (64 KB); prefetch depth stays 16 rows
#define NSK 640   // skewed-W rows per pair (638 used, padded)

// softmin constants
#define C1_ 0.28853900817779268f   // log2(e)/5
#define C2D 3.4657359027997265     // 5*ln(2), double

__device__ __forceinline__ float wred_sum(float v) {
#pragma unroll
  for (int o = 32; o > 0; o >>= 1) v += __shfl_down(v, o);
  return v;  // lane 0 holds the total
}

__device__ __forceinline__ int dexp(double x) {
  // biased-exponent field - 1023; 0.0 -> -1023 (safe "very small" marker)
  return (int)((__double_as_longlong(x) >> 52) & 0x7ff) - 1023;
}

// async global->LDS DMA, 16 B per lane: LDS dest = base + lane*16 (HW),
// global src = per-lane address. Increments vmcnt.
__device__ __forceinline__ void dma16(const float* g, float* l) {
  __builtin_amdgcn_global_load_lds(
      (const __attribute__((address_space(1))) void*)g,
      (__attribute__((address_space(3))) void*)l, 16, 0, 0);
}

// ---------------------------------------------------------------------------
// Kernel 1: pairwise sq-dist GEMM; epilogue stores W = exp(-D/gamma) in
// STAGGER-SKEWED + WITHIN-ROW-PERMUTED layout:
//   skew row n = i + 2*(j>>3); within row, lane g8's cols 8g8..8g8+3 live at
//   float offset 4*g8, cols 8g8+4..+7 at 256+4*g8.
// -> DTW's per-superstep working set = 2 contiguous 2 KB rows (coalesced DMA)
//    AND its ds_read is the 16B/lane pattern measured conflict-free (r9).
// ---------------------------------------------------------------------------
__global__ __launch_bounds__(256) void gemm_kernel(
    const float* __restrict__ data, float* __restrict__ wbuf, int pair0) {
  __shared__ float Xs[64][65];
  __shared__ float Ys[64][65];
  __shared__ float nrmx[64];
  __shared__ float nrmy[64];

  const int tile = blockIdx.x;   // 0..63 = (bi<<3)|bj
  const int pc = blockIdx.y;     // pair within chunk
  const int p = pair0 + pc;
  const int w = p / 15;
  const int o = p - w * 15;
  const int aidx = w * STEPW;
  const int oidx = aidx + 1 + o;
  const int i0 = (tile >> 3) << 6;
  const int j0 = (tile & 7) << 6;
  const int tid = threadIdx.x;

  const float* Xg = data + (size_t)aidx * (T_ * DF);
  const float* Yg = data + (size_t)oidx * (T_ * DF);

#pragma unroll
  for (int l = 0; l < 4; ++l) {
    int idx = tid + l * 256;  // 0..1023
    int r = idx >> 4;
    int c = idx & 15;
    float4 xv = reinterpret_cast<const float4*>(Xg + (size_t)(i0 + r) * DF)[c];
    float4 yv = reinterpret_cast<const float4*>(Yg + (size_t)(j0 + r) * DF)[c];
    Xs[r][4 * c + 0] = xv.x; Xs[r][4 * c + 1] = xv.y;
    Xs[r][4 * c + 2] = xv.z; Xs[r][4 * c + 3] = xv.w;
    Ys[r][4 * c + 0] = yv.x; Ys[r][4 * c + 1] = yv.y;
    Ys[r][4 * c + 2] = yv.z; Ys[r][4 * c + 3] = yv.w;
  }
  __syncthreads();

  if (tid < 128) {
    int r = tid & 63;
    const float* row = (tid < 64) ? Xs[r] : Ys[r];
    float s = 0.f;
#pragma unroll
    for (int k = 0; k < 64; ++k) s = fmaf(row[k], row[k], s);
    if (tid < 64) nrmx[r] = s; else nrmy[r] = s;
  }
  __syncthreads();

  const int tx = tid & 15;
  const int ty = tid >> 4;
  float acc[4][4];
#pragma unroll
  for (int a = 0; a < 4; ++a)
#pragma unroll
    for (int b = 0; b < 4; ++b) acc[a][b] = 0.f;

#pragma unroll 4
  for (int k = 0; k < 64; ++k) {
    float xr[4], yr[4];
#pragma unroll
    for (int a = 0; a < 4; ++a) xr[a] = Xs[ty * 4 + a][k];
#pragma unroll
    for (int b = 0; b < 4; ++b) yr[b] = Ys[tx * 4 + b][k];
#pragma unroll
    for (int a = 0; a < 4; ++a)
#pragma unroll
      for (int b = 0; b < 4; ++b) acc[a][b] = fmaf(xr[a], yr[b], acc[a][b]);
  }

  // epilogue: my float4 (cols j0+4tx..+3) belongs to lane g8 = (j0>>3)+(tx>>1);
  // dest float offset = (tx&1)*256 + 4*g8, skew row = i0+ii+2*g8.
  const int g8 = (j0 >> 3) + (tx >> 1);
  const int off = ((tx & 1) << 8) + 4 * g8;
  float* Wp = wbuf + (size_t)pc * (NSK * T_) + off;
#pragma unroll
  for (int a = 0; a < 4; ++a) {
    int ii = ty * 4 + a;
    float nx = nrmx[ii];
    float4 v;
    v.x = __builtin_exp2f(-(nx + nrmy[tx * 4 + 0] - 2.f * acc[a][0]) * C1_);
    v.y = __builtin_exp2f(-(nx + nrmy[tx * 4 + 1] - 2.f * acc[a][1]) * C1_);
    v.z = __builtin_exp2f(-(nx + nrmy[tx * 4 + 2] - 2.f * acc[a][2]) * C1_);
    v.w = __builtin_exp2f(-(nx + nrmy[tx * 4 + 3] - 2.f * acc[a][3]) * C1_);
    *reinterpret_cast<float4*>(Wp + (size_t)(i0 + ii + 2 * g8) * T_) = v;
  }
}

// ---------------------------------------------------------------------------
// Kernel 2: softDTW, exp-domain fp64 + per-lane block exponent; TWO ROWS per
// superstep (amortizes the per-step overhead r10/r12 proved dominant).
// Lane l owns cols [8l,8l+8); superstep m computes rows i=2(m-l), i+1.
// Boundaries: shuffles of lane l-1's end-of-(m-1) state {e7A=row i, e7=row
// i+1, S}; row A's diag needs lane l-1's row i-1 = 1-superstep-delayed e7.
// W staging: 32-slot LDS ring, coalesced DMAs, wait vmcnt(24) (28 in flight,
// never drained), refill +16 rows ahead (8 supersteps of ds_read slack).
// ---------------------------------------------------------------------------
__global__ __launch_bounds__(64) void dtw_kernel(
    const float* __restrict__ Wm, const int* __restrict__ lens,
    float* __restrict__ dist, int pair0) {
  __shared__ float slot[RING * T_];  // 32 slots x 2048 B = 64 KB

  const int pc = blockIdx.x;
  const int p = pair0 + pc;
  const int w = p / 15;
  const int o = p - w * 15;
  const int lx = lens[w * STEPW];
  const int ly = lens[w * STEPW + 1 + o];
  const int l = threadIdx.x;
  const int imax = lx - 1;
  const int jt = ly - 1;
  const int lt = jt >> 3, ct = jt & 7;
  const int M = lt + (imax >> 1);  // last superstep needed by lane lt
  const float invl = 1.f / (float)(lx + ly);

  const float* wp = Wm + (size_t)pc * (NSK * T_);

  // one skewed row R -> slot R%32 (2 x 1KB coalesced DMAs)
#define ISSUE(R)                                                       \
  {                                                                    \
    int r_ = (R);                                                      \
    r_ = (r_ > 637) ? 637 : r_;                                        \
    const float* gb_ = wp + (size_t)r_ * T_ + (l << 2);                \
    float* lb_ = &slot[((R) & (RING - 1)) * T_];                       \
    dma16(gb_, lb_);                                                   \
    dma16(gb_ + 256, lb_ + 256);                                       \
  }

  // prologue: rows 0..15 in flight (32 DMAs)
  ISSUE(0);  ISSUE(1);  ISSUE(2);  ISSUE(3);
  ISSUE(4);  ISSUE(5);  ISSUE(6);  ISSUE(7);
  ISSUE(8);  ISSUE(9);  ISSUE(10); ISSUE(11);
  ISSUE(12); ISSUE(13); ISSUE(14); ISSUE(15);

  // committed-row E (fp64 mantissas, shared block exponent S); e7A = row-A e7
  double e0 = 0., e1 = 0., e2 = 0., e3 = 0.;
  double e4 = 0., e5 = 0., e6 = 0., e7 = 0.;
  double e7A = 0.;
  int S = NEGS;

  // 1-superstep-delayed neighbor row-B value (for row A's diagonal)
  double pvB = 0.;  int psB = NEGS;

  // wait rows 0,1; read them as current W regs
  asm volatile("s_waitcnt vmcnt(28)" ::: "memory");
  __builtin_amdgcn_sched_barrier(0);
  float4 cA0 = *reinterpret_cast<const float4*>(&slot[0 * T_ + 4 * l]);
  float4 cA1 = *reinterpret_cast<const float4*>(&slot[0 * T_ + 256 + 4 * l]);
  float4 cB0 = *reinterpret_cast<const float4*>(&slot[1 * T_ + 4 * l]);
  float4 cB1 = *reinterpret_cast<const float4*>(&slot[1 * T_ + 256 + 4 * l]);

  for (int m = 0; m <= M; ++m) {
    // lane l-1's end-of-(m-1) state: rows i=2(m-l) and i+1, scale
    double nvA = __shfl_up(e7A, 1);
    double nvB = __shfl_up(e7, 1);
    int ns = __shfl_up(S, 1);
    const int i = 2 * (m - l);

    // boundary operands (value, scale): row A left/diag, row B left/diag
    double lA = nvA, dA = pvB, lB = nvB, dB2 = nvA;
    int slA = ns, sdA = psB, slB = ns, sdB = ns;
    if (l == 0) {
      lA = 0.; slA = NEGS;
      dA = (i == 0) ? 1. : 0.; sdA = (i == 0) ? 0 : NEGS;
      lB = 0.; slB = NEGS;
      dB2 = 0.; sdB = NEGS;
    }

    // rows 2m..2m+3 guaranteed done; read next superstep's rows, refill
    asm volatile("s_waitcnt vmcnt(24)" ::: "memory");
    __builtin_amdgcn_sched_barrier(0);
    const int sN0 = ((2 * m + 2) & (RING - 1)) * T_;
    const int sN1 = ((2 * m + 3) & (RING - 1)) * T_;
    float4 nA0 = *reinterpret_cast<const float4*>(&slot[sN0 + 4 * l]);
    float4 nA1 = *reinterpret_cast<const float4*>(&slot[sN0 + 256 + 4 * l]);
    float4 nB0 = *reinterpret_cast<const float4*>(&slot[sN1 + 4 * l]);
    float4 nB1 = *reinterpret_cast<const float4*>(&slot[sN1 + 256 + 4 * l]);
    ISSUE(2 * m + 16);
    ISSUE(2 * m + 17);

    if ((unsigned)i <= (unsigned)imax) {
      // ---- row A (i), full sum-based rescale (r6 lesson: sum bounds max)
      double sum = ((e0 + e1) + (e2 + e3)) + ((e4 + e5) + (e6 + e7));
      int NA = max(S + dexp(sum), max(slA + dexp(lA), sdA + dexp(dA)));
      const int dS = S - NA;
      if (dS != 0) {
        e0 = ldexp(e0, dS); e1 = ldexp(e1, dS);
        e2 = ldexp(e2, dS); e3 = ldexp(e3, dS);
        e4 = ldexp(e4, dS); e5 = ldexp(e5, dS);
        e6 = ldexp(e6, dS); e7 = ldexp(e7, dS);
      }
      double L = ldexp(lA, slA - NA);
      double G = ldexp(dA, sdA - NA);
      const double WA0 = (double)cA0.x, WA1 = (double)cA0.y;
      const double WA2 = (double)cA0.z, WA3 = (double)cA0.w;
      const double WA4 = (double)cA1.x, WA5 = (double)cA1.y;
      const double WA6 = (double)cA1.z, WA7 = (double)cA1.w;
      double qa0 = WA0 * ((L + G) + e0);
      double qa1 = WA1 * (e1 + e0);
      double qa2 = WA2 * (e2 + e1);
      double qa3 = WA3 * (e3 + e2);
      double qa4 = WA4 * (e4 + e3);
      double qa5 = WA5 * (e5 + e4);
      double qa6 = WA6 * (e6 + e5);
      double qa7 = WA7 * (e7 + e6);
      double a0 = qa0;
      double a1 = fma(WA1, a0, qa1);
      double a2 = fma(WA2, a1, qa2);
      double a3 = fma(WA3, a2, qa3);
      double a4 = fma(WA4, a3, qa4);
      double a5 = fma(WA5, a4, qa5);
      double a6 = fma(WA6, a5, qa6);
      double a7 = fma(WA7, a6, qa7);

      if (i + 1 <= imax) {
        // ---- row B (i+1), light scale update (boundary-max guard kept)
        int NB = max(NA, max(slB + dexp(lB), sdB + dexp(dB2)));
        const int dB = NA - NB;
        if (dB != 0) {
          a0 = ldexp(a0, dB); a1 = ldexp(a1, dB);
          a2 = ldexp(a2, dB); a3 = ldexp(a3, dB);
          a4 = ldexp(a4, dB); a5 = ldexp(a5, dB);
          a6 = ldexp(a6, dB); a7 = ldexp(a7, dB);
        }
        double LB = ldexp(lB, slB - NB);
        double GB = ldexp(dB2, sdB - NB);
        const double WB0 = (double)cB0.x, WB1 = (double)cB0.y;
        const double WB2 = (double)cB0.z, WB3 = (double)cB0.w;
        const double WB4 = (double)cB1.x, WB5 = (double)cB1.y;
        const double WB6 = (double)cB1.z, WB7 = (double)cB1.w;
        double qb0 = WB0 * ((LB + GB) + a0);
        double qb1 = WB1 * (a1 + a0);
        double qb2 = WB2 * (a2 + a1);
        double qb3 = WB3 * (a3 + a2);
        double qb4 = WB4 * (a4 + a3);
        double qb5 = WB5 * (a5 + a4);
        double qb6 = WB6 * (a6 + a5);
        double qb7 = WB7 * (a7 + a6);
        e0 = qb0;
        e1 = fma(WB1, e0, qb1);
        e2 = fma(WB2, e1, qb2);
        e3 = fma(WB3, e2, qb3);
        e4 = fma(WB4, e3, qb4);
        e5 = fma(WB5, e4, qb5);
        e6 = fma(WB6, e5, qb6);
        e7 = fma(WB7, e6, qb7);
        e7A = a7;  // already aligned to NB
        S = NB;
      } else {
        // row B out of range: commit row A as the final row
        e0 = a0; e1 = a1; e2 = a2; e3 = a3;
        e4 = a4; e5 = a5; e6 = a6; e7 = a7;
        e7A = a7;
        S = NA;
      }
    }
    pvB = nvB; psB = ns;
    cA0 = nA0; cA1 = nA1; cB0 = nB0; cB1 = nB1;
  }

  // drain: outstanding DMAs must not land in a successor block's LDS
  asm volatile("s_waitcnt vmcnt(0)" ::: "memory");

  if (l == lt) {
    double out_v = (ct == 0) ? e0 : (ct == 1) ? e1 : (ct == 2) ? e2
                 : (ct == 3) ? e3 : (ct == 4) ? e4 : (ct == 5) ? e5
                 : (ct == 6) ? e6 : e7;
    double vv = (out_v > 0.) ? out_v : 1e-300;  // belt-and-braces
    double r = -C2D * (log2(vv) + (double)S);
    dist[p] = (float)(r * (double)invl);
  }
}

// ---------------------------------------------------------------------------
// Kernel 3: MMD pairwise per-feature L2 (upper triangle, mirrored)
// ---------------------------------------------------------------------------
__global__ __launch_bounds__(64) void mmd_l2_kernel(
    const float* __restrict__ data, float* __restrict__ l2buf,
    float* __restrict__ bwpart) {
  int b = blockIdx.x;  // 0..252 upper-tri (incl diag) index
  int u = 0, rem = b;
  while (rem >= 22 - u) { rem -= 22 - u; ++u; }
  int v = u + rem;
  int f = threadIdx.x;
  float s = 0.f;
  if (u != v) {
    int iu = u < 11 ? u : u + 5;
    int iv = v < 11 ? v : v + 5;
    const float* A = data + (size_t)iu * (T_ * DF) + f;
    const float* B = data + (size_t)iv * (T_ * DF) + f;
#pragma unroll 8
    for (int t = 0; t < T_; ++t) {
      float dd = A[(size_t)t * DF] - B[(size_t)t * DF];
      s = fmaf(dd, dd, s);
    }
  }
  l2buf[(size_t)(u * 22 + v) * 64 + f] = s;
  l2buf[(size_t)(v * 22 + u) * 64 + f] = s;
  float tot = wred_sum(s);
  if (f == 0) bwpart[b] = 2.f * tot;  // diag contributes exactly 0
}

// ---------------------------------------------------------------------------
// Kernel 4: MMD kernel sums per (a,c) of the 11x11 grid
// ---------------------------------------------------------------------------
__global__ __launch_bounds__(64) void mmd_k_kernel(
    const float* __restrict__ l2buf, const float* __restrict__ bwpart,
    float* __restrict__ mmdpart) {
  int b = blockIdx.x;  // 0..120
  int a = b / 11, c = b - a * 11;
  int f = threadIdx.x;
  float bs = 0.f;
  for (int k2 = f; k2 < 253; k2 += 64) bs += bwpart[k2];
  bs = wred_sum(bs);
  float bw = __shfl(bs, 0) * (1.f / (462.f * 4.f));  // /(n^2-n)/KMUL^(KNUM//2)
  float xx = l2buf[(size_t)(a * 22 + c) * 64 + f];
  float yy = l2buf[(size_t)((11 + a) * 22 + (11 + c)) * 64 + f];
  float xy = l2buf[(size_t)(a * 22 + (11 + c)) * 64 + f];
  float yx = l2buf[(size_t)((11 + a) * 22 + c) * 64 + f];
  float term = 0.f;
  float ib = 1.f / bw;
#pragma unroll
  for (int i = 0; i < 5; ++i) {
    term += expf(-xx * ib) + expf(-yy * ib) - expf(-xy * ib) - expf(-yx * ib);
    ib *= 0.5f;
  }
  float tt = wred_sum(term);
  if (f == 0) mmdpart[b] = tt;
}

// ---------------------------------------------------------------------------
// Kernel 5: finalize — triplet loss + variance + MMD mean -> out[0]
// ---------------------------------------------------------------------------
__global__ __launch_bounds__(64) void finalize_kernel(
    const float* __restrict__ dist, const float* __restrict__ mmdpart,
    float* __restrict__ out) {
  int lane = threadIdx.x;
  float lv_po = 0.f;
  float dg[5];
#pragma unroll
  for (int g = 0; g < 5; ++g) dg[g] = 0.f;
  if (lane < 8) {
    const float* dr = dist + lane * 15;
    float dn[10];
#pragma unroll
    for (int g = 0; g < 5; ++g) dg[g] = dr[g];
#pragma unroll
    for (int k = 0; k < 10; ++k) dn[k] = dr[5 + k];
    float s1 = 0.f, s2 = 0.f;
    int nz = 0;
#pragma unroll
    for (int g = 0; g < 5; ++g) {
#pragma unroll
      for (int k = 0; k < 5; ++k) {
        float v2 = dg[g] + 1.0f - dn[k];
        if (v2 > 0.f) { s1 += v2; ++nz; }
      }
#pragma unroll
      for (int k = 5; k < 10; ++k) {
        float v2 = dg[g] + 1.0f - dn[k];
        if (v2 > 0.f) { s2 += v2; ++nz; }
      }
    }
    float only_pos = (dg[0] + dg[1] + dg[2] + dg[3] + dg[4]) * 0.002f;
    float lv = (s1 * 0.7f + s2 * 0.3f) / (float)(nz + 1);
    lv_po = lv + only_pos;
  }
  float tl = wred_sum(lv_po);
  tl = __shfl(tl, 0);

  // two-pass ddof=1 variance over the 40 dg values
  float psum = dg[0] + dg[1] + dg[2] + dg[3] + dg[4];
  float tsum = wred_sum(psum);
  float mean = __shfl(tsum, 0) * (1.f / 40.f);
  float pdev = 0.f;
  if (lane < 8) {
#pragma unroll
    for (int g = 0; g < 5; ++g) {
      float dd = dg[g] - mean;
      pdev = fmaf(dd, dd, pdev);
    }
  }
  float tdev = wred_sum(pdev);
  tdev = __shfl(tdev, 0);

  float msum = 0.f;
  for (int k2 = lane; k2 < 121; k2 += 64) msum += mmdpart[k2];
  float mt = wred_sum(msum);

  if (lane == 0) {
    float total_loss = tl * (1.f / 8.f);
    float var_g = (tdev / 39.f) * 0.1f;
    float mmd = mt * (1.f / 7744.f);
    out[0] = total_loss + mmd + var_g;
  }
}

__global__ __launch_bounds__(64) void zero_out_kernel(float* __restrict__ out,
                                                      int n) {
  int i = blockIdx.x * 64 + threadIdx.x;
  if (i < n) out[i] = 0.f;
}

// ---------------------------------------------------------------------------
extern "C" void kernel_launch(void* const* d_in, const int* in_sizes, int n_in,
                              void* d_out, int out_size, void* d_ws,
                              size_t ws_size, hipStream_t stream) {
  const float* data = (const float*)d_in[0];
  const int* lens = (const int*)d_in[1];
  float* out = (float*)d_out;
  char* ws = (char*)d_ws;

  const size_t HDR = 131072;  // dist/bwpart/mmdpart/l2buf region
  const size_t per_pair = (size_t)NSK * T_ * sizeof(float);  // 1.31 MB

  // Strict workspace guard: never touch bytes beyond ws_size.
  if (ws_size < HDR + per_pair) {
    zero_out_kernel<<<dim3((out_size + 63) / 64), 64, 0, stream>>>(out,
                                                                   out_size);
    return;
  }

  float* dist = (float*)(ws + 0);        // 120 floats
  float* bwpart = (float*)(ws + 1024);   // 253 floats
  float* mmdpart = (float*)(ws + 3072);  // 121 floats
  float* l2buf = (float*)(ws + 4096);    // 22*22*64 floats = 123904 B
  float* wbuf = (float*)(ws + HDR);

  size_t avail = ws_size - HDR;
  int PC = (int)(avail / per_pair);
  if (PC > NPAIR) PC = NPAIR;

  for (int p0 = 0; p0 < NPAIR; p0 += PC) {
    int pc = (NPAIR - p0) < PC ? (NPAIR - p0) : PC;
    gemm_kernel<<<dim3(64, pc), 256, 0, stream>>>(data, wbuf, p0);
    dtw_kernel<<<dim3(pc), 64, 0, stream>>>(wbuf, lens, dist, p0);
  }
  mmd_l2_kernel<<<dim3(253), 64, 0, stream>>>(data, l2buf, bwpart);
  mmd_k_kernel<<<dim3(121), 64, 0, stream>>>(l2buf, bwpart, mmdpart);
  finalize_kernel<<<dim3(1), 64, 0, stream>>>(dist, mmdpart, out);
}